// Round 6
// baseline (1471.894 us; speedup 1.0000x reference)
//
#include <hip/hip_runtime.h>
#include <hip/hip_bf16.h>
#include <math.h>

using bf16 = __hip_bfloat16;

#define NB 4
#define C_ 96
#define NPIX 36864
#define IMG 9216
#define CH_ST 9216
#define N_ST 884736
#define HID 255
#define EPSF 1e-5f
#define TOT 3538944

// ---------------------------------------------------------------- LayerNorm
__global__ __launch_bounds__(256) void ln_kernel(const float* __restrict__ X,
                                                 float* __restrict__ Y,
                                                 const float* __restrict__ w,
                                                 const float* __restrict__ b) {
  int pix = blockIdx.x * 256 + threadIdx.x;
  if (pix >= NPIX) return;
  int n = pix / IMG, p = pix % IMG;
  const float* xp = X + (long)n * N_ST + p;
  float s = 0.f, sq = 0.f;
  for (int c = 0; c < C_; c++) { float v = xp[c * CH_ST]; s += v; sq += v * v; }
  float m = s * (1.f / C_);
  float var = fmaxf(sq * (1.f / C_) - m * m, 0.f);
  float r = rsqrtf(var + EPSF);
  float* yp = Y + (long)n * N_ST + p;
  for (int c = 0; c < C_; c++)
    yp[c * CH_ST] = (xp[c * CH_ST] - m) * r * w[c] + b[c];
}

// ------------------------------------------- transpose NCHW -> [c][n][w][h]
__global__ void trans_kernel(const float* __restrict__ Y0, float* __restrict__ Y0C) {
  __shared__ float T[32][33];
  int nc = blockIdx.z; int n = nc / C_, c = nc % C_;
  int h0 = blockIdx.x * 32, w0 = blockIdx.y * 32;
  int tx = threadIdx.x, ty = threadIdx.y;
  const float* src = Y0 + (long)n * N_ST + (long)c * CH_ST;
  for (int r = 0; r < 4; r++)
    T[ty + 8 * r][tx] = src[(h0 + ty + 8 * r) * 96 + w0 + tx];
  __syncthreads();
  float* dst = Y0C + (long)c * NPIX + (long)n * IMG;
  for (int r = 0; r < 4; r++)
    dst[(w0 + ty + 8 * r) * 96 + h0 + tx] = T[tx][ty + 8 * r];
}

// ---------------------------------------------------------------- generic GEMM
// C[m][zQ] = sum_k A[m][k]*B[k][...]; A fp32 row-major MxK.
// EPI 0: store fp32 workspace. EPI 1: out = acc + X1, store fp32 to d_out.
template<int EPI>
__global__ __launch_bounds__(256) void gemm_kernel(
    const float* __restrict__ A, const float* __restrict__ B,
    float* __restrict__ Cout, int M, int K, int NperZ,
    long bCstride, long bZstride, int batch,
    const float* __restrict__ X1, float* __restrict__ OutF) {
  __shared__ float As[32][128];
  __shared__ float Bs[32][132];
  const int tx = threadIdx.x, ty = threadIdx.y;
  const int tid = ty * 16 + tx;
  const int m0 = blockIdx.y * 128;
  const int q0 = blockIdx.x * 128;
  const int z  = blockIdx.z;
  const float* Bz = B + (long)z * bZstride;
  float acc[8][8];
  #pragma unroll
  for (int a = 0; a < 8; a++)
    #pragma unroll
    for (int b = 0; b < 8; b++) acc[a][b] = 0.f;

  for (int kk = 0; kk < K; kk += 32) {
    #pragma unroll
    for (int it = 0; it < 16; it++) {
      int i = tid + it * 256;
      int c = i >> 7, r = i & 127;
      int mm = m0 + r, kc = kk + c;
      As[c][r] = (mm < M && kc < K) ? A[(long)mm * K + kc] : 0.f;
    }
    #pragma unroll
    for (int it = 0; it < 16; it++) {
      int i = tid + it * 256;
      int c = i >> 7, q = i & 127;
      int kc = kk + c;
      Bs[c][q] = (kc < K) ? Bz[(long)kc * bCstride + q0 + q] : 0.f;
    }
    __syncthreads();
    for (int kc = 0; kc < 32; kc++) {
      float4 a0 = *(const float4*)&As[kc][ty * 8];
      float4 a1 = *(const float4*)&As[kc][ty * 8 + 4];
      float4 b0 = *(const float4*)&Bs[kc][tx * 8];
      float4 b1 = *(const float4*)&Bs[kc][tx * 8 + 4];
      float av[8] = {a0.x, a0.y, a0.z, a0.w, a1.x, a1.y, a1.z, a1.w};
      float bv[8] = {b0.x, b0.y, b0.z, b0.w, b1.x, b1.y, b1.z, b1.w};
      #pragma unroll
      for (int a = 0; a < 8; a++)
        #pragma unroll
        for (int b = 0; b < 8; b++)
          acc[a][b] = fmaf(av[a], bv[b], acc[a][b]);
    }
    __syncthreads();
  }
  const long oStride = (long)NperZ * gridDim.z;
  if (EPI == 0) {
    #pragma unroll
    for (int a = 0; a < 8; a++) {
      int mm = m0 + ty * 8 + a;
      if (mm < M) {
        float* dst = Cout + (long)mm * oStride + (long)z * NperZ + q0 + tx * 8;
        *(float4*)dst       = make_float4(acc[a][0], acc[a][1], acc[a][2], acc[a][3]);
        *(float4*)(dst + 4) = make_float4(acc[a][4], acc[a][5], acc[a][6], acc[a][7]);
      }
    }
  } else {
    int Q = q0 + tx * 8;
    int n = batch + Q / IMG, p = Q % IMG;
    #pragma unroll
    for (int a = 0; a < 8; a++) {
      int mm = m0 + ty * 8 + a;
      if (mm < M) {
        long base = (long)n * N_ST + (long)mm * CH_ST + p;
        #pragma unroll
        for (int b = 0; b < 8; b++)
          OutF[base + b] = acc[a][b] + X1[base + b];
      }
    }
  }
}

// -------------------------------- per-channel BN stats over a [o][36864] row
__global__ __launch_bounds__(256) void rowstat_kernel(const float* __restrict__ D,
                                                      const float* __restrict__ g,
                                                      const float* __restrict__ b,
                                                      float2* __restrict__ aff) {
  int o = blockIdx.x;
  const float4* p = (const float4*)(D + (long)o * NPIX);
  float s = 0.f, sq = 0.f;
  for (int i = threadIdx.x; i < NPIX / 4; i += 256) {
    float4 v = p[i];
    s  += v.x + v.y + v.z + v.w;
    sq += v.x * v.x + v.y * v.y + v.z * v.z + v.w * v.w;
  }
  for (int off = 32; off; off >>= 1) { s += __shfl_down(s, off); sq += __shfl_down(sq, off); }
  __shared__ float ss[4], ssq[4];
  int wv = threadIdx.x >> 6, lane = threadIdx.x & 63;
  if (lane == 0) { ss[wv] = s; ssq[wv] = sq; }
  __syncthreads();
  if (threadIdx.x == 0) {
    float S = ss[0] + ss[1] + ss[2] + ss[3];
    float SQ = ssq[0] + ssq[1] + ssq[2] + ssq[3];
    float m = S / (float)NPIX;
    float var = fmaxf(SQ / (float)NPIX - m * m, 0.f);
    float sc = g[o] * rsqrtf(var + EPSF);
    aff[o] = make_float2(sc, b[o] - m * sc);
  }
}

// ------------------------------- sim (qk/qr/kr) global stats, one block=(bb,g)
__global__ __launch_bounds__(256) void simstat_kernel(const float* __restrict__ QKV,
                                                      const float2* __restrict__ aff,
                                                      const float* __restrict__ relp,
                                                      float* __restrict__ stats) {
  int bb = blockIdx.x >> 3, g = blockIdx.x & 7;
  __shared__ float qs[12][96];
  __shared__ float rl[12][191];
  __shared__ float red[6];
  int tid = threadIdx.x;
  for (int i = tid; i < 12 * 96; i += 256) {
    int c = i / 96, l = i % 96;
    int o = g * 24 + c;
    float2 a = aff[o];
    qs[c][l] = QKV[(long)o * NPIX + bb * 96 + l] * a.x + a.y;
  }
  for (int i = tid; i < 12 * 191; i += 256) (&rl[0][0])[i] = relp[i];
  if (tid < 6) red[tid] = 0.f;
  __syncthreads();
  float p0 = 0, p1 = 0, p2 = 0, sq0 = 0, sq1 = 0, sq2 = 0;
  for (int tile = tid; tile < 576; tile += 256) {
    int ti = (tile / 24) * 4, tj = (tile % 24) * 4;
    float aqk[4][4] = {}, aqr[4][4] = {}, akr[4][4] = {};
    int d0 = ti - tj + 92, e0 = tj - ti + 92;
    for (int c = 0; c < 6; c++) {
      float qv[4], kv[4], rq[7], rk[7];
      #pragma unroll
      for (int u = 0; u < 4; u++) { qv[u] = qs[c][ti + u]; kv[u] = qs[6 + c][tj + u]; }
      #pragma unroll
      for (int u = 0; u < 7; u++) { rq[u] = rl[c][d0 + u]; rk[u] = rl[6 + c][e0 + u]; }
      #pragma unroll
      for (int i = 0; i < 4; i++)
        #pragma unroll
        for (int j = 0; j < 4; j++) {
          aqk[i][j] = fmaf(qv[i], kv[j], aqk[i][j]);
          aqr[i][j] = fmaf(qv[i], rq[i - j + 3], aqr[i][j]);
          akr[i][j] = fmaf(kv[j], rk[j - i + 3], akr[i][j]);
        }
    }
    #pragma unroll
    for (int i = 0; i < 4; i++)
      #pragma unroll
      for (int j = 0; j < 4; j++) {
        p0 += aqk[i][j]; sq0 = fmaf(aqk[i][j], aqk[i][j], sq0);
        p1 += aqr[i][j]; sq1 = fmaf(aqr[i][j], aqr[i][j], sq1);
        p2 += akr[i][j]; sq2 = fmaf(akr[i][j], akr[i][j], sq2);
      }
  }
  for (int off = 32; off; off >>= 1) {
    p0 += __shfl_down(p0, off); p1 += __shfl_down(p1, off); p2 += __shfl_down(p2, off);
    sq0 += __shfl_down(sq0, off); sq1 += __shfl_down(sq1, off); sq2 += __shfl_down(sq2, off);
  }
  if ((tid & 63) == 0) {
    atomicAdd(&red[0], p0); atomicAdd(&red[1], p1); atomicAdd(&red[2], p2);
    atomicAdd(&red[3], sq0); atomicAdd(&red[4], sq1); atomicAdd(&red[5], sq2);
  }
  __syncthreads();
  if (tid < 3) {
    atomicAdd(&stats[(tid * 8 + g) * 2 + 0], red[tid]);
    atomicAdd(&stats[(tid * 8 + g) * 2 + 1], red[tid + 3]);
  }
}

__global__ void simfin_kernel(const float* __restrict__ stats,
                              const float* __restrict__ gsim,
                              float* __restrict__ scale) {
  int t = threadIdx.x;
  if (t < 24) {
    float cnt = 384.f * 9216.f;
    float m = stats[t * 2] / cnt;
    float var = fmaxf(stats[t * 2 + 1] / cnt - m * m, 0.f);
    scale[t] = gsim[t] * rsqrtf(var + EPSF);
  }
}

// ------------------- attention: logits -> softmax -> sv/sve, block = (bb,g)
__global__ __launch_bounds__(256) void attn_kernel(const float* __restrict__ QKV,
                                                   const float2* __restrict__ aff,
                                                   const float* __restrict__ relp,
                                                   const float* __restrict__ sscale,
                                                   float* __restrict__ OutPre) {
  int bb = blockIdx.x >> 3, g = blockIdx.x & 7;
  __shared__ float qs[12][96];
  __shared__ float vs[12][96];
  __shared__ float rl[12][191];   // phase1: relq/relk ; phase2b: relv
  __shared__ float P[96][100];
  __shared__ float rinv[96];
  int tid = threadIdx.x;
  for (int i = tid; i < 24 * 96; i += 256) {
    int c = i / 96, l = i % 96;
    int o = g * 24 + c;
    float2 a = aff[o];
    float v = QKV[(long)o * NPIX + bb * 96 + l] * a.x + a.y;
    if (c < 12) qs[c][l] = v; else vs[c - 12][l] = v;
  }
  for (int i = tid; i < 12 * 191; i += 256) (&rl[0][0])[i] = relp[i];
  __syncthreads();
  float s0 = sscale[g], s1 = sscale[8 + g], s2 = sscale[16 + g];
  for (int tile = tid; tile < 576; tile += 256) {
    int ti = (tile / 24) * 4, tj = (tile % 24) * 4;
    float ap[4][4] = {};
    int d0 = ti - tj + 92, e0 = tj - ti + 92;
    for (int c = 0; c < 6; c++) {
      float qv[4], kv[4], kv0[4], rq[7], rk[7];
      #pragma unroll
      for (int u = 0; u < 4; u++) {
        qv[u] = qs[c][ti + u]; kv[u] = qs[6 + c][tj + u]; kv0[u] = s0 * kv[u];
      }
      #pragma unroll
      for (int u = 0; u < 7; u++) { rq[u] = s1 * rl[c][d0 + u]; rk[u] = s2 * rl[6 + c][e0 + u]; }
      #pragma unroll
      for (int i = 0; i < 4; i++)
        #pragma unroll
        for (int j = 0; j < 4; j++) {
          ap[i][j] = fmaf(qv[i], kv0[j], ap[i][j]);
          ap[i][j] = fmaf(qv[i], rq[i - j + 3], ap[i][j]);
          ap[i][j] = fmaf(kv[j], rk[j - i + 3], ap[i][j]);
        }
    }
    #pragma unroll
    for (int i = 0; i < 4; i++)
      #pragma unroll
      for (int j = 0; j < 4; j++) P[ti + i][tj + j] = ap[i][j];
  }
  __syncthreads();
  if (tid < 96) {
    int i = tid;
    float mx = -1e30f;
    for (int j = 0; j < 96; j++) mx = fmaxf(mx, P[i][j]);
    float sum = 0.f;
    for (int j = 0; j < 96; j++) {
      float e = expf(P[i][j] - mx);
      P[i][j] = e; sum += e;
    }
    rinv[i] = 1.f / sum;
  }
  __syncthreads();
  for (int i = tid; i < 12 * 191; i += 256)
    (&rl[0][0])[i] = relp[12 * 191 + i];
  __syncthreads();
  {
    int og = tid >> 5, ig = tid & 31;
    int orb = og * 3, ib = ig * 3;
    float acc[3][3] = {};
    for (int jq = 0; jq < 24; jq++) {
      int j0 = jq * 4;
      float4 pv[3];
      #pragma unroll
      for (int u = 0; u < 3; u++) pv[u] = *(const float4*)&P[ib + u][j0];
      #pragma unroll
      for (int u = 0; u < 3; u++) {
        int orr = orb + u, cc = orr >> 1;
        if ((orr & 1) == 0) {
          float4 vv = *(const float4*)&vs[cc][j0];
          #pragma unroll
          for (int t2 = 0; t2 < 3; t2++)
            acc[u][t2] += pv[t2].x * vv.x + pv[t2].y * vv.y + pv[t2].z * vv.z + pv[t2].w * vv.w;
        } else {
          const float* rv = rl[cc];
          #pragma unroll
          for (int t2 = 0; t2 < 3; t2++) {
            int i = ib + t2;
            acc[u][t2] += pv[t2].x * rv[i - j0 + 95] + pv[t2].y * rv[i - j0 + 94]
                        + pv[t2].z * rv[i - j0 + 93] + pv[t2].w * rv[i - j0 + 92];
          }
        }
      }
    }
    #pragma unroll
    for (int u = 0; u < 3; u++)
      #pragma unroll
      for (int t2 = 0; t2 < 3; t2++) {
        int orr = orb + u, i = ib + t2;
        OutPre[(long)(g * 24 + orr) * NPIX + bb * 96 + i] = acc[u][t2] * rinv[i];
      }
  }
}

// -------- pass1 BN-apply + pair-sum + transpose to NCHW
__global__ void apply1_kernel(const float* __restrict__ OutPre,
                              const float2* __restrict__ aff,
                              float* __restrict__ Y1) {
  __shared__ float T[32][33];
  int z = blockIdx.z; int n = z / C_, cf = z % C_;
  int h0 = blockIdx.x * 32, w0 = blockIdx.y * 32;
  int tx = threadIdx.x, ty = threadIdx.y;
  float2 a0 = aff[2 * cf], a1 = aff[2 * cf + 1];
  const float* r0 = OutPre + (long)(2 * cf) * NPIX + (long)n * IMG;
  const float* r1 = OutPre + (long)(2 * cf + 1) * NPIX + (long)n * IMG;
  for (int r = 0; r < 4; r++) {
    int w = w0 + ty + 8 * r;
    int idx = w * 96 + h0 + tx;
    T[ty + 8 * r][tx] = (r0[idx] * a0.x + a0.y) + (r1[idx] * a1.x + a1.y);
  }
  __syncthreads();
  float* dst = Y1 + (long)n * N_ST + (long)cf * CH_ST;
  for (int r = 0; r < 4; r++)
    dst[(h0 + ty + 8 * r) * 96 + w0 + tx] = T[tx][ty + 8 * r];
}

// -------- pass2 BN-apply + pair-sum + residual with x
__global__ __launch_bounds__(256) void apply2_kernel(const float* __restrict__ OutPre,
                                                     const float2* __restrict__ aff,
                                                     const float* __restrict__ X,
                                                     float* __restrict__ X1out) {
  int idx = blockIdx.x * 256 + threadIdx.x;
  if (idx >= TOT) return;
  int n = idx / N_ST;
  int rem = idx % N_ST;
  int cf = rem / CH_ST;
  int p = rem % CH_ST;
  long off = (long)n * IMG + p;
  float2 a0 = aff[2 * cf], a1 = aff[2 * cf + 1];
  float v = OutPre[(long)(2 * cf) * NPIX + off] * a0.x + a0.y
          + OutPre[(long)(2 * cf + 1) * NPIX + off] * a1.x + a1.y
          + X[idx];
  X1out[idx] = v;
}

// ---------------- depthwise 3x3 SAME + GEGLU, per-batch slice
__global__ __launch_bounds__(256) void dwglu_kernel(const float* __restrict__ H,
                                                    const float* __restrict__ Wdw,
                                                    float* __restrict__ Gout) {
  int idx = blockIdx.x * 256 + threadIdx.x;
  if (idx >= HID * IMG) return;
  int c = idx / IMG;
  int p = idx % IMG, y = p / 96, x = p % 96;
  const float* h1 = H + (long)c * IMG;
  const float* h2 = H + (long)(c + HID) * IMG;
  const float* w1 = Wdw + c * 9;
  const float* w2 = Wdw + (c + HID) * 9;
  float acc1 = 0.f, acc2 = 0.f;
  #pragma unroll
  for (int dy = -1; dy <= 1; dy++) {
    int yy = y + dy; if (yy < 0 || yy >= 96) continue;
    #pragma unroll
    for (int dx = -1; dx <= 1; dx++) {
      int xx = x + dx; if (xx < 0 || xx >= 96) continue;
      int wi = (dy + 1) * 3 + dx + 1;
      acc1 = fmaf(h1[yy * 96 + xx], w1[wi], acc1);
      acc2 = fmaf(h2[yy * 96 + xx], w2[wi], acc2);
    }
  }
  float ge = 0.5f * acc1 * (1.f + erff(acc1 * 0.70710678118654752f));
  Gout[idx] = ge * acc2;
}

// ============================================================== launcher
extern "C" void kernel_launch(void* const* d_in, const int* in_sizes, int n_in,
                              void* d_out, int out_size, void* d_ws, size_t ws_size,
                              hipStream_t stream) {
  const float* x       = (const float*)d_in[0];
  const float* ln1w    = (const float*)d_in[1];
  const float* ln1b    = (const float*)d_in[2];
  const float* h_wqkv  = (const float*)d_in[3];
  const float* h_gqkv  = (const float*)d_in[4];
  const float* h_bqkv  = (const float*)d_in[5];
  const float* h_rel   = (const float*)d_in[6];
  const float* h_gsim  = (const float*)d_in[7];
  const float* h_gout  = (const float*)d_in[9];
  const float* h_bout  = (const float*)d_in[10];
  const float* w_wqkv  = (const float*)d_in[11];
  const float* w_gqkv  = (const float*)d_in[12];
  const float* w_bqkv  = (const float*)d_in[13];
  const float* w_rel   = (const float*)d_in[14];
  const float* w_gsim  = (const float*)d_in[15];
  const float* w_gout  = (const float*)d_in[17];
  const float* w_bout  = (const float*)d_in[18];
  const float* ln2w    = (const float*)d_in[19];
  const float* ln2b    = (const float*)d_in[20];
  const float* ffn_win = (const float*)d_in[21];
  const float* ffn_wdw = (const float*)d_in[22];
  const float* ffn_wout= (const float*)d_in[23];
  float* out = (float*)d_out;   // reference output dtype is float32

  float* ws = (float*)d_ws;
  float* P = ws;
  float* Q = ws + 3538944;
  float* R = ws + 7077888;
  float* S = ws + 14155776;
  float* stats = ws + 21233664;
  const size_t need_bytes = (21233664ull + 1024ull) * 4ull;
  if (ws_size < need_bytes) return;

  float2* qkv_aff = (float2*)stats;
  float2* out_aff = (float2*)(stats + 384);
  float*  sim_st  = stats + 768;
  float*  sim_sc  = stats + 864;

  hipMemsetAsync(sim_st, 0, 96 * sizeof(float), stream);

  dim3 b256(256), b1616(16, 16), b328(32, 8);

  ln_kernel<<<144, b256, 0, stream>>>(x, P, ln1w, ln1b);
  trans_kernel<<<dim3(3, 3, 384), b328, 0, stream>>>(P, Q);

  // ---- pass 1 (attention along H) ----
  gemm_kernel<0><<<dim3(288, 2, 1), b1616, 0, stream>>>(h_wqkv, Q, R,
      192, 96, 36864, 36864L, 0L, 0, nullptr, nullptr);
  rowstat_kernel<<<192, b256, 0, stream>>>(R, h_gqkv, h_bqkv, qkv_aff);
  simstat_kernel<<<3072, b256, 0, stream>>>(R, qkv_aff, h_rel, sim_st);
  simfin_kernel<<<1, 32, 0, stream>>>(sim_st, h_gsim, sim_sc);
  attn_kernel<<<3072, b256, 0, stream>>>(R, qkv_aff, h_rel, sim_sc, S);
  rowstat_kernel<<<192, b256, 0, stream>>>(S, h_gout, h_bout, out_aff);
  apply1_kernel<<<dim3(3, 3, 384), b328, 0, stream>>>(S, out_aff, P);

  // ---- pass 2 (attention along W) ----
  gemm_kernel<0><<<dim3(72, 2, 4), b1616, 0, stream>>>(w_wqkv, P, R,
      192, 96, 9216, 9216L, 884736L, 0, nullptr, nullptr);
  rowstat_kernel<<<192, b256, 0, stream>>>(R, w_gqkv, w_bqkv, qkv_aff);
  simstat_kernel<<<3072, b256, 0, stream>>>(R, qkv_aff, w_rel, sim_st + 48);
  simfin_kernel<<<1, 32, 0, stream>>>(sim_st + 48, w_gsim, sim_sc + 24);
  attn_kernel<<<3072, b256, 0, stream>>>(R, qkv_aff, w_rel, sim_sc + 24, S);
  rowstat_kernel<<<192, b256, 0, stream>>>(S, w_gout, w_bout, out_aff);
  apply2_kernel<<<13824, b256, 0, stream>>>(S, out_aff, x, P);

  // ---- FFN (batch-split) ----
  ln_kernel<<<144, b256, 0, stream>>>(P, Q, ln2w, ln2b);
  for (int n = 0; n < NB; n++) {
    gemm_kernel<0><<<dim3(72, 4, 1), b1616, 0, stream>>>(ffn_win, Q + (long)n * N_ST, R,
        510, 96, 9216, 9216L, 0L, 0, nullptr, nullptr);
    dwglu_kernel<<<9180, b256, 0, stream>>>(R, ffn_wdw, S);
    gemm_kernel<1><<<dim3(72, 1, 1), b1616, 0, stream>>>(ffn_wout, S, nullptr,
        96, 255, 9216, 9216L, 0L, n, P, out);
  }
}

// Round 7
// 1393.630 us; speedup vs baseline: 1.0562x; 1.0562x over previous
//
#include <hip/hip_runtime.h>
#include <hip/hip_bf16.h>
#include <math.h>

using bf16 = __hip_bfloat16;

#define NB 4
#define C_ 96
#define NPIX 36864
#define IMG 9216
#define CH_ST 9216
#define N_ST 884736
#define HID 255
#define EPSF 1e-5f
#define TOT 3538944

// ---------------------------------------------------------------- LayerNorm
__global__ __launch_bounds__(256) void ln_kernel(const float* __restrict__ X,
                                                 float* __restrict__ Y,
                                                 const float* __restrict__ w,
                                                 const float* __restrict__ b) {
  int pix = blockIdx.x * 256 + threadIdx.x;
  if (pix >= NPIX) return;
  int n = pix / IMG, p = pix % IMG;
  const float* xp = X + (long)n * N_ST + p;
  float s = 0.f, sq = 0.f;
  for (int c = 0; c < C_; c++) { float v = xp[c * CH_ST]; s += v; sq += v * v; }
  float m = s * (1.f / C_);
  float var = fmaxf(sq * (1.f / C_) - m * m, 0.f);
  float r = rsqrtf(var + EPSF);
  float* yp = Y + (long)n * N_ST + p;
  for (int c = 0; c < C_; c++)
    yp[c * CH_ST] = (xp[c * CH_ST] - m) * r * w[c] + b[c];
}

// ------------------------------------------- transpose NCHW -> [c][n][w][h]
__global__ void trans_kernel(const float* __restrict__ Y0, float* __restrict__ Y0C) {
  __shared__ float T[32][33];
  int nc = blockIdx.z; int n = nc / C_, c = nc % C_;
  int h0 = blockIdx.x * 32, w0 = blockIdx.y * 32;
  int tx = threadIdx.x, ty = threadIdx.y;
  const float* src = Y0 + (long)n * N_ST + (long)c * CH_ST;
  for (int r = 0; r < 4; r++)
    T[ty + 8 * r][tx] = src[(h0 + ty + 8 * r) * 96 + w0 + tx];
  __syncthreads();
  float* dst = Y0C + (long)c * NPIX + (long)n * IMG;
  for (int r = 0; r < 4; r++)
    dst[(w0 + ty + 8 * r) * 96 + h0 + tx] = T[tx][ty + 8 * r];
}

// ---------------------------------------------------------------- generic GEMM
template<int EPI>
__global__ __launch_bounds__(256) void gemm_kernel(
    const float* __restrict__ A, const float* __restrict__ B,
    float* __restrict__ Cout, int M, int K, int NperZ,
    long bCstride, long bZstride, int batch,
    const float* __restrict__ X1, float* __restrict__ OutF) {
  __shared__ float As[32][128];
  __shared__ float Bs[32][132];
  const int tx = threadIdx.x, ty = threadIdx.y;
  const int tid = ty * 16 + tx;
  const int m0 = blockIdx.y * 128;
  const int q0 = blockIdx.x * 128;
  const int z  = blockIdx.z;
  const float* Bz = B + (long)z * bZstride;
  float acc[8][8];
  #pragma unroll
  for (int a = 0; a < 8; a++)
    #pragma unroll
    for (int b = 0; b < 8; b++) acc[a][b] = 0.f;

  for (int kk = 0; kk < K; kk += 32) {
    #pragma unroll
    for (int it = 0; it < 16; it++) {
      int i = tid + it * 256;
      int c = i >> 7, r = i & 127;
      int mm = m0 + r, kc = kk + c;
      As[c][r] = (mm < M && kc < K) ? A[(long)mm * K + kc] : 0.f;
    }
    #pragma unroll
    for (int it = 0; it < 16; it++) {
      int i = tid + it * 256;
      int c = i >> 7, q = i & 127;
      int kc = kk + c;
      Bs[c][q] = (kc < K) ? Bz[(long)kc * bCstride + q0 + q] : 0.f;
    }
    __syncthreads();
    for (int kc = 0; kc < 32; kc++) {
      float4 a0 = *(const float4*)&As[kc][ty * 8];
      float4 a1 = *(const float4*)&As[kc][ty * 8 + 4];
      float4 b0 = *(const float4*)&Bs[kc][tx * 8];
      float4 b1 = *(const float4*)&Bs[kc][tx * 8 + 4];
      float av[8] = {a0.x, a0.y, a0.z, a0.w, a1.x, a1.y, a1.z, a1.w};
      float bv[8] = {b0.x, b0.y, b0.z, b0.w, b1.x, b1.y, b1.z, b1.w};
      #pragma unroll
      for (int a = 0; a < 8; a++)
        #pragma unroll
        for (int b = 0; b < 8; b++)
          acc[a][b] = fmaf(av[a], bv[b], acc[a][b]);
    }
    __syncthreads();
  }
  const long oStride = (long)NperZ * gridDim.z;
  if (EPI == 0) {
    #pragma unroll
    for (int a = 0; a < 8; a++) {
      int mm = m0 + ty * 8 + a;
      if (mm < M) {
        float* dst = Cout + (long)mm * oStride + (long)z * NperZ + q0 + tx * 8;
        *(float4*)dst       = make_float4(acc[a][0], acc[a][1], acc[a][2], acc[a][3]);
        *(float4*)(dst + 4) = make_float4(acc[a][4], acc[a][5], acc[a][6], acc[a][7]);
      }
    }
  } else {
    int Q = q0 + tx * 8;
    int n = batch + Q / IMG, p = Q % IMG;
    #pragma unroll
    for (int a = 0; a < 8; a++) {
      int mm = m0 + ty * 8 + a;
      if (mm < M) {
        long base = (long)n * N_ST + (long)mm * CH_ST + p;
        #pragma unroll
        for (int b = 0; b < 8; b++)
          OutF[base + b] = acc[a][b] + X1[base + b];
      }
    }
  }
}

// -------------------------------- per-channel BN stats over a [o][36864] row
__global__ __launch_bounds__(256) void rowstat_kernel(const float* __restrict__ D,
                                                      const float* __restrict__ g,
                                                      const float* __restrict__ b,
                                                      float2* __restrict__ aff) {
  int o = blockIdx.x;
  const float4* p = (const float4*)(D + (long)o * NPIX);
  float s = 0.f, sq = 0.f;
  for (int i = threadIdx.x; i < NPIX / 4; i += 256) {
    float4 v = p[i];
    s  += v.x + v.y + v.z + v.w;
    sq += v.x * v.x + v.y * v.y + v.z * v.z + v.w * v.w;
  }
  for (int off = 32; off; off >>= 1) { s += __shfl_down(s, off); sq += __shfl_down(sq, off); }
  __shared__ float ss[4], ssq[4];
  int wv = threadIdx.x >> 6, lane = threadIdx.x & 63;
  if (lane == 0) { ss[wv] = s; ssq[wv] = sq; }
  __syncthreads();
  if (threadIdx.x == 0) {
    float S = ss[0] + ss[1] + ss[2] + ss[3];
    float SQ = ssq[0] + ssq[1] + ssq[2] + ssq[3];
    float m = S / (float)NPIX;
    float var = fmaxf(SQ / (float)NPIX - m * m, 0.f);
    float sc = g[o] * rsqrtf(var + EPSF);
    aff[o] = make_float2(sc, b[o] - m * sc);
  }
}

// ---------------- rel window tables: A_c[i] = sum_{d=i}^{i+95} rel_c[d],
// W_p[i] = sum_{d=i}^{i+95} rel_c[d]*rel_c'[d], p over 21 pairs c<=c'.
// side 0 = qe (rows 0..5), side 1 = ke (rows 6..11).
__global__ void relstat_kernel(const float* __restrict__ relp, float* __restrict__ tbl) {
  int i = threadIdx.x;
  if (i >= 96) return;
  for (int side = 0; side < 2; side++) {
    const float* base = relp + side * 6 * 191;
    float* A = tbl + side * 27 * 96;
    float* W = A + 6 * 96;
    #pragma unroll
    for (int c = 0; c < 6; c++) {
      float s = 0.f;
      for (int d = 0; d < 96; d++) s += base[c * 191 + i + d];
      A[c * 96 + i] = s;
    }
    int p = 0;
    for (int c = 0; c < 6; c++)
      for (int c2 = c; c2 < 6; c2++, p++) {
        float s = 0.f;
        for (int d = 0; d < 96; d++) s += base[c * 191 + i + d] * base[c2 * 191 + i + d];
        W[p * 96 + i] = s;
      }
  }
}

// ---------------- algebraic sim stats: Gram identity, no logits formed.
// sum qk = S_c Sq_c Sk_c ; sum qk^2 = S_cc' Gq Gk ; qr/kr via window tables.
// grid 384: g = blk&7, chunk = blk>>3; 8 bb per block (32 lanes each).
__global__ __launch_bounds__(256) void simstat2_kernel(const float* __restrict__ QKV,
                                                       const float2* __restrict__ aff,
                                                       const float* __restrict__ tbl,
                                                       float* __restrict__ stats) {
  int g = blockIdx.x & 7, chunk = blockIdx.x >> 3;
  int bbg = threadIdx.x >> 5, lane = threadIdx.x & 31;
  int bb = chunk * 8 + bbg;
  const float* Aq = tbl;
  const float* Wq = tbl + 6 * 96;
  const float* Ak = tbl + 27 * 96;
  const float* Wk = tbl + 27 * 96 + 6 * 96;
  float Sq[6] = {}, Sk[6] = {}, Gq[21] = {}, Gk[21] = {};
  float lq = 0.f, lsq = 0.f, lk = 0.f, lsk = 0.f;
  #pragma unroll
  for (int ii = 0; ii < 3; ii++) {
    int i = lane + 32 * ii;
    float qv[6], kv[6];
    #pragma unroll
    for (int c = 0; c < 6; c++) {
      int oq = g * 24 + c, ok = g * 24 + 6 + c;
      float2 a = aff[oq], b2 = aff[ok];
      qv[c] = QKV[(long)oq * NPIX + bb * 96 + i] * a.x + a.y;
      kv[c] = QKV[(long)ok * NPIX + bb * 96 + i] * b2.x + b2.y;
      Sq[c] += qv[c]; Sk[c] += kv[c];
      lq = fmaf(qv[c], Aq[c * 96 + i], lq);
      lk = fmaf(kv[c], Ak[c * 96 + i], lk);
    }
    int p = 0;
    #pragma unroll
    for (int c = 0; c < 6; c++)
      #pragma unroll
      for (int c2 = c; c2 < 6; c2++, p++) {
        float f = (c == c2) ? 1.f : 2.f;
        float pq = qv[c] * qv[c2], pk = kv[c] * kv[c2];
        Gq[p] += pq; Gk[p] += pk;
        lsq = fmaf(pq * f, Wq[p * 96 + i], lsq);
        lsk = fmaf(pk * f, Wk[p * 96 + i], lsk);
      }
  }
  #pragma unroll
  for (int off = 16; off; off >>= 1) {
    #pragma unroll
    for (int c = 0; c < 6; c++) { Sq[c] += __shfl_down(Sq[c], off, 32); Sk[c] += __shfl_down(Sk[c], off, 32); }
    #pragma unroll
    for (int p = 0; p < 21; p++) { Gq[p] += __shfl_down(Gq[p], off, 32); Gk[p] += __shfl_down(Gk[p], off, 32); }
    lq += __shfl_down(lq, off, 32);  lsq += __shfl_down(lsq, off, 32);
    lk += __shfl_down(lk, off, 32);  lsk += __shfl_down(lsk, off, 32);
  }
  __shared__ float red[6];
  if (threadIdx.x < 6) red[threadIdx.x] = 0.f;
  __syncthreads();
  if (lane == 0) {
    float sqk = 0.f, sqk2 = 0.f;
    #pragma unroll
    for (int c = 0; c < 6; c++) sqk += Sq[c] * Sk[c];
    int p = 0;
    #pragma unroll
    for (int c = 0; c < 6; c++)
      #pragma unroll
      for (int c2 = c; c2 < 6; c2++, p++)
        sqk2 += ((c == c2) ? 1.f : 2.f) * Gq[p] * Gk[p];
    atomicAdd(&red[0], sqk); atomicAdd(&red[3], sqk2);
    atomicAdd(&red[1], lq);  atomicAdd(&red[4], lsq);
    atomicAdd(&red[2], lk);  atomicAdd(&red[5], lsk);
  }
  __syncthreads();
  if (threadIdx.x < 3) {
    atomicAdd(&stats[(threadIdx.x * 8 + g) * 2 + 0], red[threadIdx.x]);
    atomicAdd(&stats[(threadIdx.x * 8 + g) * 2 + 1], red[threadIdx.x + 3]);
  }
}

__global__ void simfin_kernel(const float* __restrict__ stats,
                              const float* __restrict__ gsim,
                              float* __restrict__ scale) {
  int t = threadIdx.x;
  if (t < 24) {
    float cnt = 384.f * 9216.f;
    float m = stats[t * 2] / cnt;
    float var = fmaxf(stats[t * 2 + 1] / cnt - m * m, 0.f);
    scale[t] = gsim[t] * rsqrtf(var + EPSF);
  }
}

// ------------------- attention: logits -> softmax -> sv/sve, block = (bb,g)
// LDS 52.6KB -> 3 blocks/CU. qs holds q,k in phase1 then v in phase3.
__global__ __launch_bounds__(256) void attn_kernel(const float* __restrict__ QKV,
                                                   const float2* __restrict__ aff,
                                                   const float* __restrict__ relp,
                                                   const float* __restrict__ sscale,
                                                   float* __restrict__ OutPre) {
  int bb = blockIdx.x >> 3, g = blockIdx.x & 7;
  __shared__ float qs[12][96];    // phase1: q(0..5),k(6..11); phase3: v(0..11)
  __shared__ float rl[12][191];   // phase1: qe,ke ; phase3: ve
  __shared__ float P[96][100];
  __shared__ float rinv[96];
  int tid = threadIdx.x;
  for (int i = tid; i < 12 * 96; i += 256) {
    int c = i / 96, l = i % 96;
    int o = g * 24 + c;
    float2 a = aff[o];
    qs[c][l] = QKV[(long)o * NPIX + bb * 96 + l] * a.x + a.y;
  }
  for (int i = tid; i < 12 * 191; i += 256) (&rl[0][0])[i] = relp[i];
  __syncthreads();
  float s0 = sscale[g], s1 = sscale[8 + g], s2 = sscale[16 + g];
  // phase 1: combined logits
  for (int tile = tid; tile < 576; tile += 256) {
    int ti = (tile / 24) * 4, tj = (tile % 24) * 4;
    float ap[4][4] = {};
    int d0 = ti - tj + 92, e0 = tj - ti + 92;
    for (int c = 0; c < 6; c++) {
      float4 q4 = *(const float4*)&qs[c][ti];
      float4 k4 = *(const float4*)&qs[6 + c][tj];
      float qv[4] = {q4.x, q4.y, q4.z, q4.w};
      float kv[4] = {k4.x, k4.y, k4.z, k4.w};
      float kv0[4], rq[7], rk[7];
      #pragma unroll
      for (int u = 0; u < 4; u++) kv0[u] = s0 * kv[u];
      #pragma unroll
      for (int u = 0; u < 7; u++) { rq[u] = s1 * rl[c][d0 + u]; rk[u] = s2 * rl[6 + c][e0 + u]; }
      #pragma unroll
      for (int i = 0; i < 4; i++)
        #pragma unroll
        for (int j = 0; j < 4; j++) {
          ap[i][j] = fmaf(qv[i], kv0[j], ap[i][j]);
          ap[i][j] = fmaf(qv[i], rq[i - j + 3], ap[i][j]);
          ap[i][j] = fmaf(kv[j], rk[j - i + 3], ap[i][j]);
        }
    }
    #pragma unroll
    for (int i = 0; i < 4; i++)
      #pragma unroll
      for (int j = 0; j < 4; j++) P[ti + i][tj + j] = ap[i][j];
  }
  __syncthreads();
  // phase 2: restage v+ve into qs/rl (independent of P), then softmax.
  for (int i = tid; i < 12 * 96; i += 256) {
    int c = i / 96, l = i % 96;
    int o = g * 24 + 12 + c;
    float2 a = aff[o];
    qs[c][l] = QKV[(long)o * NPIX + bb * 96 + l] * a.x + a.y;
  }
  for (int i = tid; i < 12 * 191; i += 256) (&rl[0][0])[i] = relp[12 * 191 + i];
  {
    int hw = tid >> 5, l32 = tid & 31;
    for (int r = hw; r < 96; r += 8) {
      float v0 = P[r][l32], v1 = P[r][l32 + 32], v2 = P[r][l32 + 64];
      float mx = fmaxf(v0, fmaxf(v1, v2));
      #pragma unroll
      for (int off = 16; off; off >>= 1) mx = fmaxf(mx, __shfl_xor(mx, off, 32));
      float e0 = expf(v0 - mx), e1 = expf(v1 - mx), e2 = expf(v2 - mx);
      P[r][l32] = e0; P[r][l32 + 32] = e1; P[r][l32 + 64] = e2;
      float s = e0 + e1 + e2;
      #pragma unroll
      for (int off = 16; off; off >>= 1) s += __shfl_xor(s, off, 32);
      if (l32 == 0) rinv[r] = 1.f / s;
    }
  }
  __syncthreads();
  // phase 3: sv (even out-rows) / sve (odd out-rows)
  {
    int og = tid >> 5, ig = tid & 31;
    int orb = og * 3, ib = ig * 3;
    float acc[3][3] = {};
    for (int jq = 0; jq < 24; jq++) {
      int j0 = jq * 4;
      float4 pv[3];
      #pragma unroll
      for (int u = 0; u < 3; u++) pv[u] = *(const float4*)&P[ib + u][j0];
      #pragma unroll
      for (int u = 0; u < 3; u++) {
        int orr = orb + u, cc = orr >> 1;
        if ((orr & 1) == 0) {
          float4 vv = *(const float4*)&qs[cc][j0];
          #pragma unroll
          for (int t2 = 0; t2 < 3; t2++)
            acc[u][t2] += pv[t2].x * vv.x + pv[t2].y * vv.y + pv[t2].z * vv.z + pv[t2].w * vv.w;
        } else {
          const float* rv = rl[cc];
          #pragma unroll
          for (int t2 = 0; t2 < 3; t2++) {
            int i = ib + t2;
            acc[u][t2] += pv[t2].x * rv[i - j0 + 95] + pv[t2].y * rv[i - j0 + 94]
                        + pv[t2].z * rv[i - j0 + 93] + pv[t2].w * rv[i - j0 + 92];
          }
        }
      }
    }
    #pragma unroll
    for (int u = 0; u < 3; u++)
      #pragma unroll
      for (int t2 = 0; t2 < 3; t2++) {
        int orr = orb + u, i = ib + t2;
        OutPre[(long)(g * 24 + orr) * NPIX + bb * 96 + i] = acc[u][t2] * rinv[i];
      }
  }
}

// -------- pass1 BN-apply + pair-sum + transpose to NCHW
__global__ void apply1_kernel(const float* __restrict__ OutPre,
                              const float2* __restrict__ aff,
                              float* __restrict__ Y1) {
  __shared__ float T[32][33];
  int z = blockIdx.z; int n = z / C_, cf = z % C_;
  int h0 = blockIdx.x * 32, w0 = blockIdx.y * 32;
  int tx = threadIdx.x, ty = threadIdx.y;
  float2 a0 = aff[2 * cf], a1 = aff[2 * cf + 1];
  const float* r0 = OutPre + (long)(2 * cf) * NPIX + (long)n * IMG;
  const float* r1 = OutPre + (long)(2 * cf + 1) * NPIX + (long)n * IMG;
  for (int r = 0; r < 4; r++) {
    int w = w0 + ty + 8 * r;
    int idx = w * 96 + h0 + tx;
    T[ty + 8 * r][tx] = (r0[idx] * a0.x + a0.y) + (r1[idx] * a1.x + a1.y);
  }
  __syncthreads();
  float* dst = Y1 + (long)n * N_ST + (long)cf * CH_ST;
  for (int r = 0; r < 4; r++)
    dst[(h0 + ty + 8 * r) * 96 + w0 + tx] = T[tx][ty + 8 * r];
}

// -------- pass2 BN-apply + pair-sum + residual with x
__global__ __launch_bounds__(256) void apply2_kernel(const float* __restrict__ OutPre,
                                                     const float2* __restrict__ aff,
                                                     const float* __restrict__ X,
                                                     float* __restrict__ X1out) {
  int idx = blockIdx.x * 256 + threadIdx.x;
  if (idx >= TOT) return;
  int n = idx / N_ST;
  int rem = idx % N_ST;
  int cf = rem / CH_ST;
  int p = rem % CH_ST;
  long off = (long)n * IMG + p;
  float2 a0 = aff[2 * cf], a1 = aff[2 * cf + 1];
  float v = OutPre[(long)(2 * cf) * NPIX + off] * a0.x + a0.y
          + OutPre[(long)(2 * cf + 1) * NPIX + off] * a1.x + a1.y
          + X[idx];
  X1out[idx] = v;
}

// ---------------- depthwise 3x3 SAME + GEGLU, per-batch slice
__global__ __launch_bounds__(256) void dwglu_kernel(const float* __restrict__ H,
                                                    const float* __restrict__ Wdw,
                                                    float* __restrict__ Gout) {
  int idx = blockIdx.x * 256 + threadIdx.x;
  if (idx >= HID * IMG) return;
  int c = idx / IMG;
  int p = idx % IMG, y = p / 96, x = p % 96;
  const float* h1 = H + (long)c * IMG;
  const float* h2 = H + (long)(c + HID) * IMG;
  const float* w1 = Wdw + c * 9;
  const float* w2 = Wdw + (c + HID) * 9;
  float acc1 = 0.f, acc2 = 0.f;
  #pragma unroll
  for (int dy = -1; dy <= 1; dy++) {
    int yy = y + dy; if (yy < 0 || yy >= 96) continue;
    #pragma unroll
    for (int dx = -1; dx <= 1; dx++) {
      int xx = x + dx; if (xx < 0 || xx >= 96) continue;
      int wi = (dy + 1) * 3 + dx + 1;
      acc1 = fmaf(h1[yy * 96 + xx], w1[wi], acc1);
      acc2 = fmaf(h2[yy * 96 + xx], w2[wi], acc2);
    }
  }
  float ge = 0.5f * acc1 * (1.f + erff(acc1 * 0.70710678118654752f));
  Gout[idx] = ge * acc2;
}

// ============================================================== launcher
extern "C" void kernel_launch(void* const* d_in, const int* in_sizes, int n_in,
                              void* d_out, int out_size, void* d_ws, size_t ws_size,
                              hipStream_t stream) {
  const float* x       = (const float*)d_in[0];
  const float* ln1w    = (const float*)d_in[1];
  const float* ln1b    = (const float*)d_in[2];
  const float* h_wqkv  = (const float*)d_in[3];
  const float* h_gqkv  = (const float*)d_in[4];
  const float* h_bqkv  = (const float*)d_in[5];
  const float* h_rel   = (const float*)d_in[6];
  const float* h_gsim  = (const float*)d_in[7];
  const float* h_gout  = (const float*)d_in[9];
  const float* h_bout  = (const float*)d_in[10];
  const float* w_wqkv  = (const float*)d_in[11];
  const float* w_gqkv  = (const float*)d_in[12];
  const float* w_bqkv  = (const float*)d_in[13];
  const float* w_rel   = (const float*)d_in[14];
  const float* w_gsim  = (const float*)d_in[15];
  const float* w_gout  = (const float*)d_in[17];
  const float* w_bout  = (const float*)d_in[18];
  const float* ln2w    = (const float*)d_in[19];
  const float* ln2b    = (const float*)d_in[20];
  const float* ffn_win = (const float*)d_in[21];
  const float* ffn_wdw = (const float*)d_in[22];
  const float* ffn_wout= (const float*)d_in[23];
  float* out = (float*)d_out;

  float* ws = (float*)d_ws;
  float* P = ws;
  float* Q = ws + 3538944;
  float* R = ws + 7077888;
  float* S = ws + 14155776;
  float* stats = ws + 21233664;
  const size_t need_bytes = (21233664ull + 8192ull) * 4ull;
  if (ws_size < need_bytes) return;

  float2* qkv_aff = (float2*)stats;
  float2* out_aff = (float2*)(stats + 384);
  float*  sim_st  = stats + 768;        // 2 x 48
  float*  sim_sc  = stats + 864;        // 2 x 24
  float*  tbl     = stats + 1024;       // 5184 rel window tables

  hipMemsetAsync(sim_st, 0, 96 * sizeof(float), stream);

  dim3 b256(256), b1616(16, 16), b328(32, 8);

  ln_kernel<<<144, b256, 0, stream>>>(x, P, ln1w, ln1b);
  trans_kernel<<<dim3(3, 3, 384), b328, 0, stream>>>(P, Q);

  // ---- pass 1 (attention along H) ----
  gemm_kernel<0><<<dim3(288, 2, 1), b1616, 0, stream>>>(h_wqkv, Q, R,
      192, 96, 36864, 36864L, 0L, 0, nullptr, nullptr);
  rowstat_kernel<<<192, b256, 0, stream>>>(R, h_gqkv, h_bqkv, qkv_aff);
  relstat_kernel<<<1, 128, 0, stream>>>(h_rel, tbl);
  simstat2_kernel<<<384, b256, 0, stream>>>(R, qkv_aff, tbl, sim_st);
  simfin_kernel<<<1, 32, 0, stream>>>(sim_st, h_gsim, sim_sc);
  attn_kernel<<<3072, b256, 0, stream>>>(R, qkv_aff, h_rel, sim_sc, S);
  rowstat_kernel<<<192, b256, 0, stream>>>(S, h_gout, h_bout, out_aff);
  apply1_kernel<<<dim3(3, 3, 384), b328, 0, stream>>>(S, out_aff, P);

  // ---- pass 2 (attention along W) ----
  gemm_kernel<0><<<dim3(72, 2, 4), b1616, 0, stream>>>(w_wqkv, P, R,
      192, 96, 9216, 9216L, 884736L, 0, nullptr, nullptr);
  rowstat_kernel<<<192, b256, 0, stream>>>(R, w_gqkv, w_bqkv, qkv_aff);
  relstat_kernel<<<1, 128, 0, stream>>>(w_rel, tbl);
  simstat2_kernel<<<384, b256, 0, stream>>>(R, qkv_aff, tbl, sim_st + 48);
  simfin_kernel<<<1, 32, 0, stream>>>(sim_st + 48, w_gsim, sim_sc + 24);
  attn_kernel<<<3072, b256, 0, stream>>>(R, qkv_aff, w_rel, sim_sc + 24, S);
  rowstat_kernel<<<192, b256, 0, stream>>>(S, w_gout, w_bout, out_aff);
  apply2_kernel<<<13824, b256, 0, stream>>>(S, out_aff, x, P);

  // ---- FFN (batch-split) ----
  ln_kernel<<<144, b256, 0, stream>>>(P, Q, ln2w, ln2b);
  for (int n = 0; n < NB; n++) {
    gemm_kernel<0><<<dim3(72, 4, 1), b1616, 0, stream>>>(ffn_win, Q + (long)n * N_ST, R,
        510, 96, 9216, 9216L, 0L, 0, nullptr, nullptr);
    dwglu_kernel<<<9180, b256, 0, stream>>>(R, ffn_wdw, S);
    gemm_kernel<1><<<dim3(72, 1, 1), b1616, 0, stream>>>(ffn_wout, S, nullptr,
        96, 255, 9216, 9216L, 0L, n, P, out);
  }
}

// Round 8
// 957.684 us; speedup vs baseline: 1.5369x; 1.4552x over previous
//
#include <hip/hip_runtime.h>
#include <hip/hip_bf16.h>
#include <math.h>

using bf16 = __hip_bfloat16;

#define NB 4
#define C_ 96
#define NPIX 36864
#define IMG 9216
#define CH_ST 9216
#define N_ST 884736
#define HID 255
#define EPSF 1e-5f
#define TOT 3538944

// ---------------------------------------------------------------- LayerNorm
__global__ __launch_bounds__(256) void ln_kernel(const float* __restrict__ X,
                                                 float* __restrict__ Y,
                                                 const float* __restrict__ w,
                                                 const float* __restrict__ b) {
  int pix = blockIdx.x * 256 + threadIdx.x;
  if (pix >= NPIX) return;
  int n = pix / IMG, p = pix % IMG;
  const float* xp = X + (long)n * N_ST + p;
  float s = 0.f, sq = 0.f;
  for (int c = 0; c < C_; c++) { float v = xp[c * CH_ST]; s += v; sq += v * v; }
  float m = s * (1.f / C_);
  float var = fmaxf(sq * (1.f / C_) - m * m, 0.f);
  float r = rsqrtf(var + EPSF);
  float* yp = Y + (long)n * N_ST + p;
  for (int c = 0; c < C_; c++)
    yp[c * CH_ST] = (xp[c * CH_ST] - m) * r * w[c] + b[c];
}

// ------------------------------------------- transpose NCHW -> [c][n][w][h]
__global__ void trans_kernel(const float* __restrict__ Y0, float* __restrict__ Y0C) {
  __shared__ float T[32][33];
  int nc = blockIdx.z; int n = nc / C_, c = nc % C_;
  int h0 = blockIdx.x * 32, w0 = blockIdx.y * 32;
  int tx = threadIdx.x, ty = threadIdx.y;
  const float* src = Y0 + (long)n * N_ST + (long)c * CH_ST;
  for (int r = 0; r < 4; r++)
    T[ty + 8 * r][tx] = src[(h0 + ty + 8 * r) * 96 + w0 + tx];
  __syncthreads();
  float* dst = Y0C + (long)c * NPIX + (long)n * IMG;
  for (int r = 0; r < 4; r++)
    dst[(w0 + ty + 8 * r) * 96 + h0 + tx] = T[tx][ty + 8 * r];
}

// ---------------------------------------------------------------- generic GEMM
// tile 128 x TN, thread tile 8 x (TN/16). EPI0: fp32 ws. EPI1: +X1 -> d_out.
template<int TN, int EPI>
__global__ __launch_bounds__(256) void gemm_kernel(
    const float* __restrict__ A, const float* __restrict__ B,
    float* __restrict__ Cout, int M, int K, int NperZ,
    long bCstride, long bZstride, int batch,
    const float* __restrict__ X1, float* __restrict__ OutF) {
  constexpr int NT = TN / 16;
  __shared__ float As[32][128];
  __shared__ float Bs[32][TN + 4];
  const int tx = threadIdx.x, ty = threadIdx.y;
  const int tid = ty * 16 + tx;
  const int m0 = blockIdx.y * 128;
  const int q0 = blockIdx.x * TN;
  const int z  = blockIdx.z;
  const float* Bz = B + (long)z * bZstride;
  float acc[8][NT];
  #pragma unroll
  for (int a = 0; a < 8; a++)
    #pragma unroll
    for (int b = 0; b < NT; b++) acc[a][b] = 0.f;

  for (int kk = 0; kk < K; kk += 32) {
    #pragma unroll
    for (int it = 0; it < 16; it++) {
      int i = tid + it * 256;
      int c = i >> 7, r = i & 127;
      int mm = m0 + r, kc = kk + c;
      As[c][r] = (mm < M && kc < K) ? A[(long)mm * K + kc] : 0.f;
    }
    #pragma unroll
    for (int it = 0; it < (32 * TN) / 256; it++) {
      int i = tid + it * 256;
      int c = i / TN, q = i % TN;
      int kc = kk + c;
      Bs[c][q] = (kc < K) ? Bz[(long)kc * bCstride + q0 + q] : 0.f;
    }
    __syncthreads();
    for (int kc = 0; kc < 32; kc++) {
      float4 a0 = *(const float4*)&As[kc][ty * 8];
      float4 a1 = *(const float4*)&As[kc][ty * 8 + 4];
      float av[8] = {a0.x, a0.y, a0.z, a0.w, a1.x, a1.y, a1.z, a1.w};
      float bv[NT];
      #pragma unroll
      for (int v4 = 0; v4 < NT / 4; v4++) {
        float4 b4 = *(const float4*)&Bs[kc][tx * NT + v4 * 4];
        bv[v4 * 4] = b4.x; bv[v4 * 4 + 1] = b4.y; bv[v4 * 4 + 2] = b4.z; bv[v4 * 4 + 3] = b4.w;
      }
      #pragma unroll
      for (int a = 0; a < 8; a++)
        #pragma unroll
        for (int b = 0; b < NT; b++)
          acc[a][b] = fmaf(av[a], bv[b], acc[a][b]);
    }
    __syncthreads();
  }
  const long oStride = (long)NperZ * gridDim.z;
  if (EPI == 0) {
    #pragma unroll
    for (int a = 0; a < 8; a++) {
      int mm = m0 + ty * 8 + a;
      if (mm < M) {
        float* dst = Cout + (long)mm * oStride + (long)z * NperZ + q0 + tx * NT;
        #pragma unroll
        for (int v4 = 0; v4 < NT / 4; v4++)
          *(float4*)(dst + v4 * 4) = make_float4(acc[a][v4 * 4], acc[a][v4 * 4 + 1],
                                                 acc[a][v4 * 4 + 2], acc[a][v4 * 4 + 3]);
      }
    }
  } else {
    int Q = q0 + tx * NT;
    int n = batch + z + Q / IMG, p = Q % IMG;
    #pragma unroll
    for (int a = 0; a < 8; a++) {
      int mm = m0 + ty * 8 + a;
      if (mm < M) {
        long base = (long)n * N_ST + (long)mm * CH_ST + p;
        #pragma unroll
        for (int b = 0; b < NT; b++)
          OutF[base + b] = acc[a][b] + X1[base + b];
      }
    }
  }
}

// -------------------------------- per-channel BN stats over a [o][36864] row
__global__ __launch_bounds__(256) void rowstat_kernel(const float* __restrict__ D,
                                                      const float* __restrict__ g,
                                                      const float* __restrict__ b,
                                                      float2* __restrict__ aff) {
  int o = blockIdx.x;
  const float4* p = (const float4*)(D + (long)o * NPIX);
  float s = 0.f, sq = 0.f;
  for (int i = threadIdx.x; i < NPIX / 4; i += 256) {
    float4 v = p[i];
    s  += v.x + v.y + v.z + v.w;
    sq += v.x * v.x + v.y * v.y + v.z * v.z + v.w * v.w;
  }
  for (int off = 32; off; off >>= 1) { s += __shfl_down(s, off); sq += __shfl_down(sq, off); }
  __shared__ float ss[4], ssq[4];
  int wv = threadIdx.x >> 6, lane = threadIdx.x & 63;
  if (lane == 0) { ss[wv] = s; ssq[wv] = sq; }
  __syncthreads();
  if (threadIdx.x == 0) {
    float S = ss[0] + ss[1] + ss[2] + ss[3];
    float SQ = ssq[0] + ssq[1] + ssq[2] + ssq[3];
    float m = S / (float)NPIX;
    float var = fmaxf(SQ / (float)NPIX - m * m, 0.f);
    float sc = g[o] * rsqrtf(var + EPSF);
    aff[o] = make_float2(sc, b[o] - m * sc);
  }
}

// ---------------- rel window tables (parallel): block=(side,row), 96 threads
__global__ void relstat_kernel(const float* __restrict__ relp, float* __restrict__ tbl) {
  int i = threadIdx.x;
  if (i >= 96) return;
  int side = blockIdx.x / 27, row = blockIdx.x % 27;
  const float* base = relp + side * 6 * 191;
  float* T = tbl + side * 27 * 96;
  if (row < 6) {
    float s = 0.f;
    for (int d = 0; d < 96; d++) s += base[row * 191 + i + d];
    T[row * 96 + i] = s;
  } else {
    int p = row - 6, c = 0;
    while (p >= 6 - c) { p -= 6 - c; c++; }
    int c2 = c + p;
    float s = 0.f;
    for (int d = 0; d < 96; d++) s += base[c * 191 + i + d] * base[c2 * 191 + i + d];
    T[576 + (row - 6) * 96 + i] = s;
  }
}

// ---------------- algebraic sim stats (Gram identity, no logits)
__global__ __launch_bounds__(256) void simstat2_kernel(const float* __restrict__ QKV,
                                                       const float2* __restrict__ aff,
                                                       const float* __restrict__ tbl,
                                                       float* __restrict__ stats) {
  int g = blockIdx.x & 7, chunk = blockIdx.x >> 3;
  int bbg = threadIdx.x >> 5, lane = threadIdx.x & 31;
  int bb = chunk * 8 + bbg;
  const float* Aq = tbl;
  const float* Wq = tbl + 6 * 96;
  const float* Ak = tbl + 27 * 96;
  const float* Wk = tbl + 27 * 96 + 6 * 96;
  float Sq[6] = {}, Sk[6] = {}, Gq[21] = {}, Gk[21] = {};
  float lq = 0.f, lsq = 0.f, lk = 0.f, lsk = 0.f;
  #pragma unroll
  for (int ii = 0; ii < 3; ii++) {
    int i = lane + 32 * ii;
    float qv[6], kv[6];
    #pragma unroll
    for (int c = 0; c < 6; c++) {
      int oq = g * 24 + c, ok = g * 24 + 6 + c;
      float2 a = aff[oq], b2 = aff[ok];
      qv[c] = QKV[(long)oq * NPIX + bb * 96 + i] * a.x + a.y;
      kv[c] = QKV[(long)ok * NPIX + bb * 96 + i] * b2.x + b2.y;
      Sq[c] += qv[c]; Sk[c] += kv[c];
      lq = fmaf(qv[c], Aq[c * 96 + i], lq);
      lk = fmaf(kv[c], Ak[c * 96 + i], lk);
    }
    int p = 0;
    #pragma unroll
    for (int c = 0; c < 6; c++)
      #pragma unroll
      for (int c2 = c; c2 < 6; c2++, p++) {
        float f = (c == c2) ? 1.f : 2.f;
        float pq = qv[c] * qv[c2], pk = kv[c] * kv[c2];
        Gq[p] += pq; Gk[p] += pk;
        lsq = fmaf(pq * f, Wq[p * 96 + i], lsq);
        lsk = fmaf(pk * f, Wk[p * 96 + i], lsk);
      }
  }
  #pragma unroll
  for (int off = 16; off; off >>= 1) {
    #pragma unroll
    for (int c = 0; c < 6; c++) { Sq[c] += __shfl_down(Sq[c], off, 32); Sk[c] += __shfl_down(Sk[c], off, 32); }
    #pragma unroll
    for (int p = 0; p < 21; p++) { Gq[p] += __shfl_down(Gq[p], off, 32); Gk[p] += __shfl_down(Gk[p], off, 32); }
    lq += __shfl_down(lq, off, 32);  lsq += __shfl_down(lsq, off, 32);
    lk += __shfl_down(lk, off, 32);  lsk += __shfl_down(lsk, off, 32);
  }
  __shared__ float red[6];
  if (threadIdx.x < 6) red[threadIdx.x] = 0.f;
  __syncthreads();
  if (lane == 0) {
    float sqk = 0.f, sqk2 = 0.f;
    #pragma unroll
    for (int c = 0; c < 6; c++) sqk += Sq[c] * Sk[c];
    int p = 0;
    #pragma unroll
    for (int c = 0; c < 6; c++)
      #pragma unroll
      for (int c2 = c; c2 < 6; c2++, p++)
        sqk2 += ((c == c2) ? 1.f : 2.f) * Gq[p] * Gk[p];
    atomicAdd(&red[0], sqk); atomicAdd(&red[3], sqk2);
    atomicAdd(&red[1], lq);  atomicAdd(&red[4], lsq);
    atomicAdd(&red[2], lk);  atomicAdd(&red[5], lsk);
  }
  __syncthreads();
  if (threadIdx.x < 3) {
    atomicAdd(&stats[(threadIdx.x * 8 + g) * 2 + 0], red[threadIdx.x]);
    atomicAdd(&stats[(threadIdx.x * 8 + g) * 2 + 1], red[threadIdx.x + 3]);
  }
}

__global__ void simfin_kernel(const float* __restrict__ stats,
                              const float* __restrict__ gsim,
                              float* __restrict__ scale) {
  int t = threadIdx.x;
  if (t < 24) {
    float cnt = 384.f * 9216.f;
    float m = stats[t * 2] / cnt;
    float var = fmaxf(stats[t * 2 + 1] / cnt - m * m, 0.f);
    scale[t] = gsim[t] * rsqrtf(var + EPSF);
  }
}

// ------------------- attention: block = (bb, g, iq); rows i0..i0+31.
// LDS 38.0 KB -> 4 blocks/CU. All of k,v,rel resident; no restage.
__global__ __launch_bounds__(256) void attn_kernel(const float* __restrict__ QKV,
                                                   const float2* __restrict__ aff,
                                                   const float* __restrict__ relp,
                                                   const float* __restrict__ sscale,
                                                   float* __restrict__ OutPre) {
  int blk = blockIdx.x;
  int bb = blk / 24, rem = blk % 24;
  int g = rem / 3, iq = rem % 3;
  int i0 = iq * 32;
  __shared__ float qI[6][32];
  __shared__ float kF[6][96];
  __shared__ float vF[12][96];
  __shared__ float rl[24][191];   // qe 0..5, ke 6..11, ve 12..23
  __shared__ float P[32][100];
  __shared__ float rinv[32];
  int tid = threadIdx.x;
  for (int i = tid; i < 6 * 32; i += 256) {
    int c = i >> 5, l = i & 31;
    int o = g * 24 + c; float2 a = aff[o];
    qI[c][l] = QKV[(long)o * NPIX + bb * 96 + i0 + l] * a.x + a.y;
  }
  for (int i = tid; i < 6 * 96; i += 256) {
    int c = i / 96, l = i % 96;
    int o = g * 24 + 6 + c; float2 a = aff[o];
    kF[c][l] = QKV[(long)o * NPIX + bb * 96 + l] * a.x + a.y;
  }
  for (int i = tid; i < 12 * 96; i += 256) {
    int c = i / 96, l = i % 96;
    int o = g * 24 + 12 + c; float2 a = aff[o];
    vF[c][l] = QKV[(long)o * NPIX + bb * 96 + l] * a.x + a.y;
  }
  for (int i = tid; i < 24 * 191; i += 256) (&rl[0][0])[i] = relp[i];
  __syncthreads();
  float s0 = sscale[g], s1 = sscale[8 + g], s2 = sscale[16 + g];
  int hw = tid >> 5, l32 = tid & 31;
  // phase 1: logits for 32 rows; thread tile 4i x 3j (exact)
  {
    int til = hw * 4;            // local row base
    int ti = i0 + til;           // global row base
    int tj = l32 * 3;
    int d0 = ti - tj + 93;
    int e0 = tj - ti + 92;
    float ap[4][3] = {};
    #pragma unroll
    for (int c = 0; c < 6; c++) {
      float4 q4 = *(const float4*)&qI[c][til];
      float qv[4] = {q4.x, q4.y, q4.z, q4.w};
      float kv[3], kv0[3], rq[6], rk[6];
      #pragma unroll
      for (int j = 0; j < 3; j++) { kv[j] = kF[c][tj + j]; kv0[j] = s0 * kv[j]; }
      #pragma unroll
      for (int u = 0; u < 6; u++) { rq[u] = s1 * rl[c][d0 + u]; rk[u] = s2 * rl[6 + c][e0 + u]; }
      #pragma unroll
      for (int ii = 0; ii < 4; ii++)
        #pragma unroll
        for (int jj = 0; jj < 3; jj++) {
          ap[ii][jj] = fmaf(qv[ii], kv0[jj], ap[ii][jj]);
          ap[ii][jj] = fmaf(qv[ii], rq[ii - jj + 2], ap[ii][jj]);
          ap[ii][jj] = fmaf(kv[jj], rk[jj - ii + 3], ap[ii][jj]);
        }
    }
    #pragma unroll
    for (int ii = 0; ii < 4; ii++)
      #pragma unroll
      for (int jj = 0; jj < 3; jj++)
        P[til + ii][l32 * 3 + jj] = ap[ii][jj];
  }
  __syncthreads();
  // phase 2: softmax, warp per row (4 rows/warp)
  for (int r = hw; r < 32; r += 8) {
    float v0 = P[r][l32], v1 = P[r][l32 + 32], v2 = P[r][l32 + 64];
    float mx = fmaxf(v0, fmaxf(v1, v2));
    #pragma unroll
    for (int off = 16; off; off >>= 1) mx = fmaxf(mx, __shfl_xor(mx, off, 32));
    float e0 = expf(v0 - mx), e1 = expf(v1 - mx), e2 = expf(v2 - mx);
    P[r][l32] = e0; P[r][l32 + 32] = e1; P[r][l32 + 64] = e2;
    float s = e0 + e1 + e2;
    #pragma unroll
    for (int off = 16; off; off >>= 1) s += __shfl_xor(s, off, 32);
    if (l32 == 0) rinv[r] = 1.f / s;
  }
  __syncthreads();
  // phase 3: warp hw -> out rows orr0..+2; lane -> local i
  {
    int orr0 = hw * 3;
    float acc3[3] = {};
    for (int jq = 0; jq < 24; jq++) {
      int j0 = jq * 4;
      float4 pv = *(const float4*)&P[l32][j0];
      #pragma unroll
      for (int u = 0; u < 3; u++) {
        int orr = orr0 + u, cc = orr >> 1;
        if ((orr & 1) == 0) {
          float4 vv = *(const float4*)&vF[cc][j0];
          acc3[u] += pv.x * vv.x + pv.y * vv.y + pv.z * vv.z + pv.w * vv.w;
        } else {
          const float* rv = rl[12 + cc];
          int bse = (i0 + l32) - j0 + 95;
          acc3[u] += pv.x * rv[bse] + pv.y * rv[bse - 1] + pv.z * rv[bse - 2] + pv.w * rv[bse - 3];
        }
      }
    }
    #pragma unroll
    for (int u = 0; u < 3; u++)
      OutPre[(long)(g * 24 + orr0 + u) * NPIX + bb * 96 + i0 + l32] = acc3[u] * rinv[l32];
  }
}

// -------- pass1 BN-apply + pair-sum + transpose to NCHW
__global__ void apply1_kernel(const float* __restrict__ OutPre,
                              const float2* __restrict__ aff,
                              float* __restrict__ Y1) {
  __shared__ float T[32][33];
  int z = blockIdx.z; int n = z / C_, cf = z % C_;
  int h0 = blockIdx.x * 32, w0 = blockIdx.y * 32;
  int tx = threadIdx.x, ty = threadIdx.y;
  float2 a0 = aff[2 * cf], a1 = aff[2 * cf + 1];
  const float* r0 = OutPre + (long)(2 * cf) * NPIX + (long)n * IMG;
  const float* r1 = OutPre + (long)(2 * cf + 1) * NPIX + (long)n * IMG;
  for (int r = 0; r < 4; r++) {
    int w = w0 + ty + 8 * r;
    int idx = w * 96 + h0 + tx;
    T[ty + 8 * r][tx] = (r0[idx] * a0.x + a0.y) + (r1[idx] * a1.x + a1.y);
  }
  __syncthreads();
  float* dst = Y1 + (long)n * N_ST + (long)cf * CH_ST;
  for (int r = 0; r < 4; r++)
    dst[(h0 + ty + 8 * r) * 96 + w0 + tx] = T[tx][ty + 8 * r];
}

// -------- pass2 BN-apply + pair-sum + residual with x
__global__ __launch_bounds__(256) void apply2_kernel(const float* __restrict__ OutPre,
                                                     const float2* __restrict__ aff,
                                                     const float* __restrict__ X,
                                                     float* __restrict__ X1out) {
  int idx = blockIdx.x * 256 + threadIdx.x;
  if (idx >= TOT) return;
  int n = idx / N_ST;
  int rem = idx % N_ST;
  int cf = rem / CH_ST;
  int p = rem % CH_ST;
  long off = (long)n * IMG + p;
  float2 a0 = aff[2 * cf], a1 = aff[2 * cf + 1];
  float v = OutPre[(long)(2 * cf) * NPIX + off] * a0.x + a0.y
          + OutPre[(long)(2 * cf + 1) * NPIX + off] * a1.x + a1.y
          + X[idx];
  X1out[idx] = v;
}

// ---------------- depthwise 3x3 SAME + GEGLU, per-batch slice
__global__ __launch_bounds__(256) void dwglu_kernel(const float* __restrict__ H,
                                                    const float* __restrict__ Wdw,
                                                    float* __restrict__ Gout) {
  int idx = blockIdx.x * 256 + threadIdx.x;
  if (idx >= HID * IMG) return;
  int c = idx / IMG;
  int p = idx % IMG, y = p / 96, x = p % 96;
  const float* h1 = H + (long)c * IMG;
  const float* h2 = H + (long)(c + HID) * IMG;
  const float* w1 = Wdw + c * 9;
  const float* w2 = Wdw + (c + HID) * 9;
  float acc1 = 0.f, acc2 = 0.f;
  #pragma unroll
  for (int dy = -1; dy <= 1; dy++) {
    int yy = y + dy; if (yy < 0 || yy >= 96) continue;
    #pragma unroll
    for (int dx = -1; dx <= 1; dx++) {
      int xx = x + dx; if (xx < 0 || xx >= 96) continue;
      int wi = (dy + 1) * 3 + dx + 1;
      acc1 = fmaf(h1[yy * 96 + xx], w1[wi], acc1);
      acc2 = fmaf(h2[yy * 96 + xx], w2[wi], acc2);
    }
  }
  float ge = 0.5f * acc1 * (1.f + erff(acc1 * 0.70710678118654752f));
  Gout[idx] = ge * acc2;
}

// ============================================================== launcher
extern "C" void kernel_launch(void* const* d_in, const int* in_sizes, int n_in,
                              void* d_out, int out_size, void* d_ws, size_t ws_size,
                              hipStream_t stream) {
  const float* x       = (const float*)d_in[0];
  const float* ln1w    = (const float*)d_in[1];
  const float* ln1b    = (const float*)d_in[2];
  const float* h_wqkv  = (const float*)d_in[3];
  const float* h_gqkv  = (const float*)d_in[4];
  const float* h_bqkv  = (const float*)d_in[5];
  const float* h_rel   = (const float*)d_in[6];
  const float* h_gsim  = (const float*)d_in[7];
  const float* h_gout  = (const float*)d_in[9];
  const float* h_bout  = (const float*)d_in[10];
  const float* w_wqkv  = (const float*)d_in[11];
  const float* w_gqkv  = (const float*)d_in[12];
  const float* w_bqkv  = (const float*)d_in[13];
  const float* w_rel   = (const float*)d_in[14];
  const float* w_gsim  = (const float*)d_in[15];
  const float* w_gout  = (const float*)d_in[17];
  const float* w_bout  = (const float*)d_in[18];
  const float* ln2w    = (const float*)d_in[19];
  const float* ln2b    = (const float*)d_in[20];
  const float* ffn_win = (const float*)d_in[21];
  const float* ffn_wdw = (const float*)d_in[22];
  const float* ffn_wout= (const float*)d_in[23];
  float* out = (float*)d_out;

  float* ws = (float*)d_ws;
  float* P = ws;
  float* Q = ws + 3538944;
  float* R = ws + 7077888;
  float* S = ws + 14155776;
  float* Gall = R;                      // FFN: 255*36864 = 9400320 (spans R + part of S)
  float* Hbuf = ws + 16478208;          // FFN: 510*9216 = 4700160 (ends 21178368)
  float* stats = ws + 21233664;
  const size_t need_bytes = (21233664ull + 8192ull) * 4ull;
  if (ws_size < need_bytes) return;

  float2* qkv_aff = (float2*)stats;
  float2* out_aff = (float2*)(stats + 384);
  float*  sim_st  = stats + 768;
  float*  sim_sc  = stats + 864;
  float*  tbl     = stats + 1024;

  hipMemsetAsync(sim_st, 0, 96 * sizeof(float), stream);

  dim3 b256(256), b1616(16, 16), b328(32, 8);

  ln_kernel<<<144, b256, 0, stream>>>(x, P, ln1w, ln1b);
  trans_kernel<<<dim3(3, 3, 384), b328, 0, stream>>>(P, Q);

  // ---- pass 1 (attention along H) ----
  gemm_kernel<128, 0><<<dim3(288, 2, 1), b1616, 0, stream>>>(h_wqkv, Q, R,
      192, 96, 36864, 36864L, 0L, 0, nullptr, nullptr);
  rowstat_kernel<<<192, b256, 0, stream>>>(R, h_gqkv, h_bqkv, qkv_aff);
  relstat_kernel<<<54, 96, 0, stream>>>(h_rel, tbl);
  simstat2_kernel<<<384, b256, 0, stream>>>(R, qkv_aff, tbl, sim_st);
  simfin_kernel<<<1, 32, 0, stream>>>(sim_st, h_gsim, sim_sc);
  attn_kernel<<<9216, b256, 0, stream>>>(R, qkv_aff, h_rel, sim_sc, S);
  rowstat_kernel<<<192, b256, 0, stream>>>(S, h_gout, h_bout, out_aff);
  apply1_kernel<<<dim3(3, 3, 384), b328, 0, stream>>>(S, out_aff, P);

  // ---- pass 2 (attention along W) ----
  gemm_kernel<128, 0><<<dim3(72, 2, 4), b1616, 0, stream>>>(w_wqkv, P, R,
      192, 96, 9216, 9216L, 884736L, 0, nullptr, nullptr);
  rowstat_kernel<<<192, b256, 0, stream>>>(R, w_gqkv, w_bqkv, qkv_aff);
  relstat_kernel<<<54, 96, 0, stream>>>(w_rel, tbl);
  simstat2_kernel<<<384, b256, 0, stream>>>(R, qkv_aff, tbl, sim_st + 48);
  simfin_kernel<<<1, 32, 0, stream>>>(sim_st + 48, w_gsim, sim_sc + 24);
  attn_kernel<<<9216, b256, 0, stream>>>(R, qkv_aff, w_rel, sim_sc + 24, S);
  rowstat_kernel<<<192, b256, 0, stream>>>(S, w_gout, w_bout, out_aff);
  apply2_kernel<<<13824, b256, 0, stream>>>(S, out_aff, x, P);

  // ---- FFN ----
  ln_kernel<<<144, b256, 0, stream>>>(P, Q, ln2w, ln2b);
  for (int n = 0; n < NB; n++) {
    gemm_kernel<64, 0><<<dim3(144, 4, 1), b1616, 0, stream>>>(ffn_win, Q + (long)n * N_ST, Hbuf,
        510, 96, 9216, 9216L, 0L, 0, nullptr, nullptr);
    dwglu_kernel<<<9180, b256, 0, stream>>>(Hbuf, ffn_wdw, Gall + (long)n * 2350080);
  }
  gemm_kernel<64, 1><<<dim3(144, 1, 4), b1616, 0, stream>>>(ffn_wout, Gall, nullptr,
      96, 255, 9216, 9216L, 2350080L, 0, P, out);
}

// Round 11
// 908.128 us; speedup vs baseline: 1.6208x; 1.0546x over previous
//
#include <hip/hip_runtime.h>
#include <hip/hip_bf16.h>
#include <math.h>

using bf16 = __hip_bfloat16;

#define NB 4
#define C_ 96
#define NPIX 36864
#define IMG 9216
#define CH_ST 9216
#define N_ST 884736
#define HID 255
#define EPSF 1e-5f
#define TOT 3538944

// ---------------------------------------------------------------- LayerNorm
__global__ __launch_bounds__(256) void ln_kernel(const float* __restrict__ X,
                                                 float* __restrict__ Y,
                                                 const float* __restrict__ w,
                                                 const float* __restrict__ b) {
  int pix = blockIdx.x * 256 + threadIdx.x;
  if (pix >= NPIX) return;
  int n = pix / IMG, p = pix % IMG;
  const float* xp = X + (long)n * N_ST + p;
  float s = 0.f, sq = 0.f;
  for (int c = 0; c < C_; c++) { float v = xp[c * CH_ST]; s += v; sq += v * v; }
  float m = s * (1.f / C_);
  float var = fmaxf(sq * (1.f / C_) - m * m, 0.f);
  float r = rsqrtf(var + EPSF);
  float* yp = Y + (long)n * N_ST + p;
  for (int c = 0; c < C_; c++)
    yp[c * CH_ST] = (xp[c * CH_ST] - m) * r * w[c] + b[c];
}

// ------------------------------------------- transpose NCHW -> [c][n][w][h]
__global__ void trans_kernel(const float* __restrict__ Y0, float* __restrict__ Y0C) {
  __shared__ float T[32][33];
  int nc = blockIdx.z; int n = nc / C_, c = nc % C_;
  int h0 = blockIdx.x * 32, w0 = blockIdx.y * 32;
  int tx = threadIdx.x, ty = threadIdx.y;
  const float* src = Y0 + (long)n * N_ST + (long)c * CH_ST;
  for (int r = 0; r < 4; r++)
    T[ty + 8 * r][tx] = src[(h0 + ty + 8 * r) * 96 + w0 + tx];
  __syncthreads();
  float* dst = Y0C + (long)c * NPIX + (long)n * IMG;
  for (int r = 0; r < 4; r++)
    dst[(w0 + ty + 8 * r) * 96 + h0 + tx] = T[tx][ty + 8 * r];
}

// ---------------------------------------------------------------- generic GEMM
// tile 128 x TN, thread tile 8 x (TN/16). EPI0: fp32 ws. EPI1: +X1 -> d_out.
template<int TN, int EPI>
__global__ __launch_bounds__(256) void gemm_kernel(
    const float* __restrict__ A, const float* __restrict__ B,
    float* __restrict__ Cout, int M, int K, int NperZ,
    long bCstride, long bZstride, int batch,
    const float* __restrict__ X1, float* __restrict__ OutF) {
  constexpr int NT = TN / 16;
  __shared__ float As[32][128];
  __shared__ float Bs[32][TN + 4];
  const int tx = threadIdx.x, ty = threadIdx.y;
  const int tid = ty * 16 + tx;
  const int m0 = blockIdx.y * 128;
  const int q0 = blockIdx.x * TN;
  const int z  = blockIdx.z;
  const float* Bz = B + (long)z * bZstride;
  float acc[8][NT];
  #pragma unroll
  for (int a = 0; a < 8; a++)
    #pragma unroll
    for (int b = 0; b < NT; b++) acc[a][b] = 0.f;

  for (int kk = 0; kk < K; kk += 32) {
    #pragma unroll
    for (int it = 0; it < 16; it++) {
      int i = tid + it * 256;
      int c = i >> 7, r = i & 127;
      int mm = m0 + r, kc = kk + c;
      As[c][r] = (mm < M && kc < K) ? A[(long)mm * K + kc] : 0.f;
    }
    #pragma unroll
    for (int it = 0; it < (32 * TN) / 256; it++) {
      int i = tid + it * 256;
      int c = i / TN, q = i % TN;
      int kc = kk + c;
      Bs[c][q] = (kc < K) ? Bz[(long)kc * bCstride + q0 + q] : 0.f;
    }
    __syncthreads();
    for (int kc = 0; kc < 32; kc++) {
      float4 a0 = *(const float4*)&As[kc][ty * 8];
      float4 a1 = *(const float4*)&As[kc][ty * 8 + 4];
      float av[8] = {a0.x, a0.y, a0.z, a0.w, a1.x, a1.y, a1.z, a1.w};
      float bv[NT];
      #pragma unroll
      for (int v4 = 0; v4 < NT / 4; v4++) {
        float4 b4 = *(const float4*)&Bs[kc][tx * NT + v4 * 4];
        bv[v4 * 4] = b4.x; bv[v4 * 4 + 1] = b4.y; bv[v4 * 4 + 2] = b4.z; bv[v4 * 4 + 3] = b4.w;
      }
      #pragma unroll
      for (int a = 0; a < 8; a++)
        #pragma unroll
        for (int b = 0; b < NT; b++)
          acc[a][b] = fmaf(av[a], bv[b], acc[a][b]);
    }
    __syncthreads();
  }
  const long oStride = (long)NperZ * gridDim.z;
  if (EPI == 0) {
    #pragma unroll
    for (int a = 0; a < 8; a++) {
      int mm = m0 + ty * 8 + a;
      if (mm < M) {
        float* dst = Cout + (long)mm * oStride + (long)z * NperZ + q0 + tx * NT;
        #pragma unroll
        for (int v4 = 0; v4 < NT / 4; v4++)
          *(float4*)(dst + v4 * 4) = make_float4(acc[a][v4 * 4], acc[a][v4 * 4 + 1],
                                                 acc[a][v4 * 4 + 2], acc[a][v4 * 4 + 3]);
      }
    }
  } else {
    int Q = q0 + tx * NT;
    int n = batch + z + Q / IMG, p = Q % IMG;
    #pragma unroll
    for (int a = 0; a < 8; a++) {
      int mm = m0 + ty * 8 + a;
      if (mm < M) {
        long base = (long)n * N_ST + (long)mm * CH_ST + p;
        #pragma unroll
        for (int b = 0; b < NT; b++)
          OutF[base + b] = acc[a][b] + X1[base + b];
      }
    }
  }
}

// ------------------- per-channel BN stats over a [o][36864] row, 1024 thr
__global__ __launch_bounds__(1024) void rowstat_kernel(const float* __restrict__ D,
                                                       const float* __restrict__ g,
                                                       const float* __restrict__ b,
                                                       float2* __restrict__ aff) {
  int o = blockIdx.x;
  const float4* p = (const float4*)(D + (long)o * NPIX);
  float s = 0.f, sq = 0.f;
  for (int i = threadIdx.x; i < NPIX / 4; i += 1024) {
    float4 v = p[i];
    s  += v.x + v.y + v.z + v.w;
    sq += v.x * v.x + v.y * v.y + v.z * v.z + v.w * v.w;
  }
  for (int off = 32; off; off >>= 1) { s += __shfl_down(s, off); sq += __shfl_down(sq, off); }
  __shared__ float ss[16], ssq[16];
  int wv = threadIdx.x >> 6, lane = threadIdx.x & 63;
  if (lane == 0) { ss[wv] = s; ssq[wv] = sq; }
  __syncthreads();
  if (threadIdx.x == 0) {
    float S = 0.f, SQ = 0.f;
    #pragma unroll
    for (int i = 0; i < 16; i++) { S += ss[i]; SQ += ssq[i]; }
    float m = S / (float)NPIX;
    float var = fmaxf(SQ / (float)NPIX - m * m, 0.f);
    float sc = g[o] * rsqrtf(var + EPSF);
    aff[o] = make_float2(sc, b[o] - m * sc);
  }
}

// ---------------- rel window tables (parallel): block=(side,row), 96 threads
__global__ void relstat_kernel(const float* __restrict__ relp, float* __restrict__ tbl) {
  int i = threadIdx.x;
  if (i >= 96) return;
  int side = blockIdx.x / 27, row = blockIdx.x % 27;
  const float* base = relp + side * 6 * 191;
  float* T = tbl + side * 27 * 96;
  if (row < 6) {
    float s = 0.f;
    for (int d = 0; d < 96; d++) s += base[row * 191 + i + d];
    T[row * 96 + i] = s;
  } else {
    int p = row - 6, c = 0;
    while (p >= 6 - c) { p -= 6 - c; c++; }
    int c2 = c + p;
    float s = 0.f;
    for (int d = 0; d < 96; d++) s += base[c * 191 + i + d] * base[c2 * 191 + i + d];
    T[576 + (row - 6) * 96 + i] = s;
  }
}

// ---------------- algebraic sim stats (Gram identity, no logits)
__global__ __launch_bounds__(256) void simstat2_kernel(const float* __restrict__ QKV,
                                                       const float2* __restrict__ aff,
                                                       const float* __restrict__ tbl,
                                                       float* __restrict__ stats) {
  int g = blockIdx.x & 7, chunk = blockIdx.x >> 3;
  int bbg = threadIdx.x >> 5, lane = threadIdx.x & 31;
  int bb = chunk * 8 + bbg;
  const float* Aq = tbl;
  const float* Wq = tbl + 6 * 96;
  const float* Ak = tbl + 27 * 96;
  const float* Wk = tbl + 27 * 96 + 6 * 96;
  float Sq[6] = {}, Sk[6] = {}, Gq[21] = {}, Gk[21] = {};
  float lq = 0.f, lsq = 0.f, lk = 0.f, lsk = 0.f;
  #pragma unroll
  for (int ii = 0; ii < 3; ii++) {
    int i = lane + 32 * ii;
    float qv[6], kv[6];
    #pragma unroll
    for (int c = 0; c < 6; c++) {
      int oq = g * 24 + c, ok = g * 24 + 6 + c;
      float2 a = aff[oq], b2 = aff[ok];
      qv[c] = QKV[(long)oq * NPIX + bb * 96 + i] * a.x + a.y;
      kv[c] = QKV[(long)ok * NPIX + bb * 96 + i] * b2.x + b2.y;
      Sq[c] += qv[c]; Sk[c] += kv[c];
      lq = fmaf(qv[c], Aq[c * 96 + i], lq);
      lk = fmaf(kv[c], Ak[c * 96 + i], lk);
    }
    int p = 0;
    #pragma unroll
    for (int c = 0; c < 6; c++)
      #pragma unroll
      for (int c2 = c; c2 < 6; c2++, p++) {
        float f = (c == c2) ? 1.f : 2.f;
        float pq = qv[c] * qv[c2], pk = kv[c] * kv[c2];
        Gq[p] += pq; Gk[p] += pk;
        lsq = fmaf(pq * f, Wq[p * 96 + i], lsq);
        lsk = fmaf(pk * f, Wk[p * 96 + i], lsk);
      }
  }
  #pragma unroll
  for (int off = 16; off; off >>= 1) {
    #pragma unroll
    for (int c = 0; c < 6; c++) { Sq[c] += __shfl_down(Sq[c], off, 32); Sk[c] += __shfl_down(Sk[c], off, 32); }
    #pragma unroll
    for (int p = 0; p < 21; p++) { Gq[p] += __shfl_down(Gq[p], off, 32); Gk[p] += __shfl_down(Gk[p], off, 32); }
    lq += __shfl_down(lq, off, 32);  lsq += __shfl_down(lsq, off, 32);
    lk += __shfl_down(lk, off, 32);  lsk += __shfl_down(lsk, off, 32);
  }
  __shared__ float red[6];
  if (threadIdx.x < 6) red[threadIdx.x] = 0.f;
  __syncthreads();
  if (lane == 0) {
    float sqk = 0.f, sqk2 = 0.f;
    #pragma unroll
    for (int c = 0; c < 6; c++) sqk += Sq[c] * Sk[c];
    int p = 0;
    #pragma unroll
    for (int c = 0; c < 6; c++)
      #pragma unroll
      for (int c2 = c; c2 < 6; c2++, p++)
        sqk2 += ((c == c2) ? 1.f : 2.f) * Gq[p] * Gk[p];
    atomicAdd(&red[0], sqk); atomicAdd(&red[3], sqk2);
    atomicAdd(&red[1], lq);  atomicAdd(&red[4], lsq);
    atomicAdd(&red[2], lk);  atomicAdd(&red[5], lsk);
  }
  __syncthreads();
  if (threadIdx.x < 3) {
    atomicAdd(&stats[(threadIdx.x * 8 + g) * 2 + 0], red[threadIdx.x]);
    atomicAdd(&stats[(threadIdx.x * 8 + g) * 2 + 1], red[threadIdx.x + 3]);
  }
}

__global__ void simfin_kernel(const float* __restrict__ stats,
                              const float* __restrict__ gsim,
                              float* __restrict__ scale) {
  int t = threadIdx.x;
  if (t < 24) {
    float cnt = 384.f * 9216.f;
    float m = stats[t * 2] / cnt;
    float var = fmaxf(stats[t * 2 + 1] / cnt - m * m, 0.f);
    scale[t] = gsim[t] * rsqrtf(var + EPSF);
  }
}

// ------------------- attention: block = (bb, g, iq); rows i0..i0+31.
// LDS 38.5 KB -> 4 blocks/CU. s1/s2 folded into rel staging; kF raw.
__global__ __launch_bounds__(256) void attn_kernel(const float* __restrict__ QKV,
                                                   const float2* __restrict__ aff,
                                                   const float* __restrict__ relp,
                                                   const float* __restrict__ sscale,
                                                   float* __restrict__ OutPre) {
  int blk = blockIdx.x;
  int bb = blk / 24, rem = blk % 24;
  int g = rem / 3, iq = rem % 3;
  int i0 = iq * 32;
  __shared__ float qI[6][32];
  __shared__ float kF[6][96];    // raw k (kr term needs it unscaled)
  __shared__ float vF[12][96];
  __shared__ float rl[24][191];  // 0..5 qe*s1, 6..11 ke*s2, 12..23 ve
  __shared__ float P[32][100];
  __shared__ float rinv[32];
  int tid = threadIdx.x;
  float s0 = sscale[g], s1 = sscale[8 + g], s2 = sscale[16 + g];
  for (int i = tid; i < 6 * 32; i += 256) {
    int c = i >> 5, l = i & 31;
    int o = g * 24 + c; float2 a = aff[o];
    qI[c][l] = QKV[(long)o * NPIX + bb * 96 + i0 + l] * a.x + a.y;
  }
  for (int i = tid; i < 6 * 96; i += 256) {
    int c = i / 96, l = i % 96;
    int o = g * 24 + 6 + c; float2 a = aff[o];
    kF[c][l] = QKV[(long)o * NPIX + bb * 96 + l] * a.x + a.y;
  }
  for (int i = tid; i < 12 * 96; i += 256) {
    int c = i / 96, l = i % 96;
    int o = g * 24 + 12 + c; float2 a = aff[o];
    vF[c][l] = QKV[(long)o * NPIX + bb * 96 + l] * a.x + a.y;
  }
  for (int i = tid; i < 24 * 191; i += 256) {
    int r = i / 191;
    float sc = (r < 6) ? s1 : ((r < 12) ? s2 : 1.f);
    (&rl[0][0])[i] = relp[i] * sc;
  }
  __syncthreads();
  int hw = tid >> 5, l32 = tid & 31;
  // phase 1: logits; thread tile 4i x 3j (exact cover of 32x96)
  {
    int til = hw * 4;
    int ti = i0 + til;
    int tj = l32 * 3;
    int d0 = ti - tj + 93;
    int e0 = tj - ti + 92;
    float ap[4][3] = {};
    #pragma unroll
    for (int c = 0; c < 6; c++) {
      float4 q4 = *(const float4*)&qI[c][til];
      float qv[4] = {q4.x, q4.y, q4.z, q4.w};
      float kv[3], kv0[3], rq[6], rk[6];
      #pragma unroll
      for (int j = 0; j < 3; j++) { kv[j] = kF[c][tj + j]; kv0[j] = s0 * kv[j]; }
      #pragma unroll
      for (int u = 0; u < 6; u++) { rq[u] = rl[c][d0 + u]; rk[u] = rl[6 + c][e0 + u]; }
      #pragma unroll
      for (int ii = 0; ii < 4; ii++)
        #pragma unroll
        for (int jj = 0; jj < 3; jj++) {
          ap[ii][jj] = fmaf(qv[ii], kv0[jj], ap[ii][jj]);
          ap[ii][jj] = fmaf(qv[ii], rq[ii - jj + 2], ap[ii][jj]);
          ap[ii][jj] = fmaf(kv[jj], rk[jj - ii + 3], ap[ii][jj]);
        }
    }
    #pragma unroll
    for (int ii = 0; ii < 4; ii++)
      #pragma unroll
      for (int jj = 0; jj < 3; jj++)
        P[til + ii][l32 * 3 + jj] = ap[ii][jj];
  }
  __syncthreads();
  // phase 2: softmax, warp per row (4 rows/warp), hw exp
  for (int r = hw; r < 32; r += 8) {
    float v0 = P[r][l32], v1 = P[r][l32 + 32], v2 = P[r][l32 + 64];
    float mx = fmaxf(v0, fmaxf(v1, v2));
    #pragma unroll
    for (int off = 16; off; off >>= 1) mx = fmaxf(mx, __shfl_xor(mx, off, 32));
    float e0 = __expf(v0 - mx), e1 = __expf(v1 - mx), e2 = __expf(v2 - mx);
    P[r][l32] = e0; P[r][l32 + 32] = e1; P[r][l32 + 64] = e2;
    float s = e0 + e1 + e2;
    #pragma unroll
    for (int off = 16; off; off >>= 1) s += __shfl_xor(s, off, 32);
    if (l32 == 0) rinv[r] = 1.f / s;
  }
  __syncthreads();
  // phase 3: warp hw -> out rows orr0..orr0+2; lane -> local i; ascending rel reads
  {
    int orr0 = hw * 3;
    float acc3[3] = {};
    for (int jq = 0; jq < 24; jq++) {
      int j0 = jq * 4;
      float4 pv = *(const float4*)&P[l32][j0];
      #pragma unroll
      for (int u = 0; u < 3; u++) {
        int orr = orr0 + u, cc = orr >> 1;
        if ((orr & 1) == 0) {
          float4 vv = *(const float4*)&vF[cc][j0];
          acc3[u] += pv.x * vv.x + pv.y * vv.y + pv.z * vv.z + pv.w * vv.w;
        } else {
          const float* rv = rl[12 + cc];
          int bse = (i0 + l32) - j0 + 92;
          float f0 = rv[bse], f1 = rv[bse + 1], f2 = rv[bse + 2], f3 = rv[bse + 3];
          acc3[u] += pv.w * f0 + pv.z * f1 + pv.y * f2 + pv.x * f3;
        }
      }
    }
    #pragma unroll
    for (int u = 0; u < 3; u++)
      OutPre[(long)(g * 24 + orr0 + u) * NPIX + bb * 96 + i0 + l32] = acc3[u] * rinv[l32];
  }
}

// -------- pass1 BN-apply + pair-sum + transpose to NCHW
__global__ void apply1_kernel(const float* __restrict__ OutPre,
                              const float2* __restrict__ aff,
                              float* __restrict__ Y1) {
  __shared__ float T[32][33];
  int z = blockIdx.z; int n = z / C_, cf = z % C_;
  int h0 = blockIdx.x * 32, w0 = blockIdx.y * 32;
  int tx = threadIdx.x, ty = threadIdx.y;
  float2 a0 = aff[2 * cf], a1 = aff[2 * cf + 1];
  const float* r0 = OutPre + (long)(2 * cf) * NPIX + (long)n * IMG;
  const float* r1 = OutPre + (long)(2 * cf + 1) * NPIX + (long)n * IMG;
  for (int r = 0; r < 4; r++) {
    int w = w0 + ty + 8 * r;
    int idx = w * 96 + h0 + tx;
    T[ty + 8 * r][tx] = (r0[idx] * a0.x + a0.y) + (r1[idx] * a1.x + a1.y);
  }
  __syncthreads();
  float* dst = Y1 + (long)n * N_ST + (long)cf * CH_ST;
  for (int r = 0; r < 4; r++)
    dst[(h0 + ty + 8 * r) * 96 + w0 + tx] = T[tx][ty + 8 * r];
}

// -------- pass2 BN-apply + pair-sum + residual with x
__global__ __launch_bounds__(256) void apply2_kernel(const float* __restrict__ OutPre,
                                                     const float2* __restrict__ aff,
                                                     const float* __restrict__ X,
                                                     float* __restrict__ X1out) {
  int idx = blockIdx.x * 256 + threadIdx.x;
  if (idx >= TOT) return;
  int n = idx / N_ST;
  int rem = idx % N_ST;
  int cf = rem / CH_ST;
  int p = rem % CH_ST;
  long off = (long)n * IMG + p;
  float2 a0 = aff[2 * cf], a1 = aff[2 * cf + 1];
  float v = OutPre[(long)(2 * cf) * NPIX + off] * a0.x + a0.y
          + OutPre[(long)(2 * cf + 1) * NPIX + off] * a1.x + a1.y
          + X[idx];
  X1out[idx] = v;
}

// ---------------- depthwise 3x3 SAME + GEGLU, per-batch slice
__global__ __launch_bounds__(256) void dwglu_kernel(const float* __restrict__ H,
                                                    const float* __restrict__ Wdw,
                                                    float* __restrict__ Gout) {
  int idx = blockIdx.x * 256 + threadIdx.x;
  if (idx >= HID * IMG) return;
  int c = idx / IMG;
  int p = idx % IMG, y = p / 96, x = p % 96;
  const float* h1 = H + (long)c * IMG;
  const float* h2 = H + (long)(c + HID) * IMG;
  const float* w1 = Wdw + c * 9;
  const float* w2 = Wdw + (c + HID) * 9;
  float acc1 = 0.f, acc2 = 0.f;
  #pragma unroll
  for (int dy = -1; dy <= 1; dy++) {
    int yy = y + dy; if (yy < 0 || yy >= 96) continue;
    #pragma unroll
    for (int dx = -1; dx <= 1; dx++) {
      int xx = x + dx; if (xx < 0 || xx >= 96) continue;
      int wi = (dy + 1) * 3 + dx + 1;
      acc1 = fmaf(h1[yy * 96 + xx], w1[wi], acc1);
      acc2 = fmaf(h2[yy * 96 + xx], w2[wi], acc2);
    }
  }
  float ge = 0.5f * acc1 * (1.f + erff(acc1 * 0.70710678118654752f));
  Gout[idx] = ge * acc2;
}

// ============================================================== launcher
extern "C" void kernel_launch(void* const* d_in, const int* in_sizes, int n_in,
                              void* d_out, int out_size, void* d_ws, size_t ws_size,
                              hipStream_t stream) {
  const float* x       = (const float*)d_in[0];
  const float* ln1w    = (const float*)d_in[1];
  const float* ln1b    = (const float*)d_in[2];
  const float* h_wqkv  = (const float*)d_in[3];
  const float* h_gqkv  = (const float*)d_in[4];
  const float* h_bqkv  = (const float*)d_in[5];
  const float* h_rel   = (const float*)d_in[6];
  const float* h_gsim  = (const float*)d_in[7];
  const float* h_gout  = (const float*)d_in[9];
  const float* h_bout  = (const float*)d_in[10];
  const float* w_wqkv  = (const float*)d_in[11];
  const float* w_gqkv  = (const float*)d_in[12];
  const float* w_bqkv  = (const float*)d_in[13];
  const float* w_rel   = (const float*)d_in[14];
  const float* w_gsim  = (const float*)d_in[15];
  const float* w_gout  = (const float*)d_in[17];
  const float* w_bout  = (const float*)d_in[18];
  const float* ln2w    = (const float*)d_in[19];
  const float* ln2b    = (const float*)d_in[20];
  const float* ffn_win = (const float*)d_in[21];
  const float* ffn_wdw = (const float*)d_in[22];
  const float* ffn_wout= (const float*)d_in[23];
  float* out = (float*)d_out;

  float* ws = (float*)d_ws;
  float* P = ws;
  float* Q = ws + 3538944;
  float* R = ws + 7077888;
  float* S = ws + 14155776;
  float* Gall = R;
  float* Hbuf = ws + 16478208;
  float* stats = ws + 21233664;
  const size_t need_bytes = (21233664ull + 8192ull) * 4ull;
  if (ws_size < need_bytes) return;

  float2* qkv_aff = (float2*)stats;
  float2* out_aff = (float2*)(stats + 384);
  float*  sim_st  = stats + 768;
  float*  sim_sc  = stats + 864;
  float*  tbl     = stats + 1024;

  hipMemsetAsync(sim_st, 0, 96 * sizeof(float), stream);

  dim3 b256(256), b1616(16, 16), b328(32, 8);

  ln_kernel<<<144, b256, 0, stream>>>(x, P, ln1w, ln1b);
  trans_kernel<<<dim3(3, 3, 384), b328, 0, stream>>>(P, Q);

  // ---- pass 1 (attention along H) ----
  gemm_kernel<128, 0><<<dim3(288, 2, 1), b1616, 0, stream>>>(h_wqkv, Q, R,
      192, 96, 36864, 36864L, 0L, 0, nullptr, nullptr);
  rowstat_kernel<<<192, 1024, 0, stream>>>(R, h_gqkv, h_bqkv, qkv_aff);
  relstat_kernel<<<54, 96, 0, stream>>>(h_rel, tbl);
  simstat2_kernel<<<384, b256, 0, stream>>>(R, qkv_aff, tbl, sim_st);
  simfin_kernel<<<1, 32, 0, stream>>>(sim_st, h_gsim, sim_sc);
  attn_kernel<<<9216, b256, 0, stream>>>(R, qkv_aff, h_rel, sim_sc, S);
  rowstat_kernel<<<192, 1024, 0, stream>>>(S, h_gout, h_bout, out_aff);
  apply1_kernel<<<dim3(3, 3, 384), b328, 0, stream>>>(S, out_aff, P);

  // ---- pass 2 (attention along W) ----
  gemm_kernel<128, 0><<<dim3(72, 2, 4), b1616, 0, stream>>>(w_wqkv, P, R,
      192, 96, 9216, 9216L, 884736L, 0, nullptr, nullptr);
  rowstat_kernel<<<192, 1024, 0, stream>>>(R, w_gqkv, w_bqkv, qkv_aff);
  relstat_kernel<<<54, 96, 0, stream>>>(w_rel, tbl);
  simstat2_kernel<<<384, b256, 0, stream>>>(R, qkv_aff, tbl, sim_st + 48);
  simfin_kernel<<<1, 32, 0, stream>>>(sim_st + 48, w_gsim, sim_sc + 24);
  attn_kernel<<<9216, b256, 0, stream>>>(R, qkv_aff, w_rel, sim_sc + 24, S);
  rowstat_kernel<<<192, 1024, 0, stream>>>(S, w_gout, w_bout, out_aff);
  apply2_kernel<<<13824, b256, 0, stream>>>(S, out_aff, x, P);

  // ---- FFN ----
  ln_kernel<<<144, b256, 0, stream>>>(P, Q, ln2w, ln2b);
  for (int n = 0; n < NB; n++) {
    gemm_kernel<64, 0><<<dim3(144, 4, 1), b1616, 0, stream>>>(ffn_win, Q + (long)n * N_ST, Hbuf,
        510, 96, 9216, 9216L, 0L, 0, nullptr, nullptr);
    dwglu_kernel<<<9180, b256, 0, stream>>>(Hbuf, ffn_wdw, Gall + (long)n * 2350080);
  }
  gemm_kernel<64, 1><<<dim3(144, 1, 4), b1616, 0, stream>>>(ffn_wout, Gall, nullptr,
      96, 255, 9216, 9216L, 2350080L, 0, P, out);
}